// Round 1
// baseline (1353.716 us; speedup 1.0000x reference)
//
#include <hip/hip_runtime.h>

#define NNODES 100000
#define NEDGES 1600000
#define PLANE_ELT ((size_t)NNODES * 16)

typedef __attribute__((ext_vector_type(8))) short bf16x8;
typedef __attribute__((ext_vector_type(4))) float f32x4;
typedef __attribute__((ext_vector_type(2))) float f32x2;

// ---------- bf16 helpers ----------
__device__ __forceinline__ float bf2f(unsigned v) {
  union { unsigned u; float f; } x; x.u = v << 16; return x.f;
}
__device__ __forceinline__ unsigned short f2bf(float f) {
  union { float f; unsigned u; } x; x.f = f;
  unsigned r = x.u + 0x7fffu + ((x.u >> 16) & 1u);
  return (unsigned short)(r >> 16);
}

// ---------- dtype probing ----------
__global__ void k_probe(const unsigned* __restrict__ xw, const int* __restrict__ ei,
                        int* __restrict__ flags) {
  __shared__ int cF, cI;
  if (threadIdx.x == 0) { cF = 0; cI = 0; }
  __syncthreads();
  int t = threadIdx.x;
  int hf = 0;
  for (int i = t; i < 2048; i += 256) {
    unsigned lo = xw[i] & 0xffffu;
    unsigned e = (lo >> 7) & 0xffu;
    if (e >= 0xC0u) hf++;
  }
  atomicAdd(&cF, hf);
  int hi = 0;
  if (ei[2 * t + 1] != 0) hi++;
  atomicAdd(&cI, hi);
  __syncthreads();
  if (threadIdx.x == 0) {
    flags[0] = (cF > 32) ? 1 : 0;
    flags[1] = (cI < 16) ? 1 : 0;
  }
}

__device__ __forceinline__ int edge_at(const int* __restrict__ ei, int j, int i64) {
  return i64 ? ei[2 * j] : ei[j];
}

// ---------- canonicalize float arrays to bf16 ----------
// array 0 (x) is written in 16-col plane layout [8][N][16]; others flat.
struct CvtParams {
  const void* src[13];
  unsigned short* dst[13];
  int n[13];
};

__global__ void k_cvt(CvtParams p, const int* __restrict__ flags) {
  int a = blockIdx.y;
  int n = p.n[a];
  int f32 = flags[0];
  const float* sf = (const float*)p.src[a];
  const unsigned short* sb = (const unsigned short*)p.src[a];
  unsigned short* d = p.dst[a];
  for (int i = blockIdx.x * blockDim.x + threadIdx.x; i < n; i += gridDim.x * blockDim.x) {
    unsigned short val = f32 ? f2bf(sf[i]) : sb[i];
    if (a == 0) {
      int v = i >> 7, c = i & 127;
      d[(size_t)(c >> 4) * PLANE_ELT + (size_t)v * 16 + (c & 15)] = val;
    } else {
      d[i] = val;
    }
  }
}

// transpose W[K,256] -> WT[256,K]
__global__ void k_transpose(const unsigned short* __restrict__ W,
                            unsigned short* __restrict__ WT, int K) {
  int idx = blockIdx.x * 256 + threadIdx.x;
  if (idx < K * 256) {
    int k = idx >> 8, c = idx & 255;
    WT[c * K + k] = W[idx];
  }
}

// transpose W[K,40] -> WT[48,K], rows 40..47 zero
template <int K>
__global__ void k_transpose40(const unsigned short* __restrict__ W,
                              unsigned short* __restrict__ WT) {
  int idx = blockIdx.x * 256 + threadIdx.x;
  if (idx < 48 * K) {
    int c = idx / K, k = idx % K;
    WT[idx] = (c < 40) ? W[k * 40 + c] : (unsigned short)0;
  }
}

__global__ void k_zero(int* __restrict__ p, int n) {
  int v = blockIdx.x * blockDim.x + threadIdx.x;
  if (v < n) p[v] = 0;
}

// ---------- graph preprocessing ----------
__global__ void k_count(const int* __restrict__ ei, int* __restrict__ cnt,
                        const int* __restrict__ flags) {
  int e = blockIdx.x * blockDim.x + threadIdx.x;
  if (e < NEDGES) {
    int i64 = flags[1];
    int d = edge_at(ei, NEDGES + e, i64);
    if ((unsigned)d < NNODES) atomicAdd(&cnt[d], 1);
  }
}

__global__ void k_dinv(const int* __restrict__ cnt, float* __restrict__ dinv) {
  int v = blockIdx.x * blockDim.x + threadIdx.x;
  if (v < NNODES) dinv[v] = rsqrtf((float)cnt[v] + 1.0f);
}

// ---------- parallel scan ----------
__global__ void k_psum(const int* __restrict__ cnt, int* __restrict__ bsum) {
  __shared__ int sw[4];
  int t = threadIdx.x;
  int i = blockIdx.x * 256 + t;
  int v = (i < NNODES) ? cnt[i] : 0;
  int x = v;
#pragma unroll
  for (int o = 1; o < 64; o <<= 1) {
    int y = __shfl_up(x, o, 64);
    if ((t & 63) >= o) x += y;
  }
  if ((t & 63) == 63) sw[t >> 6] = x;
  __syncthreads();
  if (t == 0) bsum[blockIdx.x] = sw[0] + sw[1] + sw[2] + sw[3];
}

__global__ void k_bscan(const int* __restrict__ bsum, int* __restrict__ bbase,
                        int* __restrict__ offs) {
  int l = threadIdx.x;
  int base = l * 7;
  int v[7];
  int s = 0;
#pragma unroll
  for (int k = 0; k < 7; ++k) {
    int j = base + k;
    v[k] = (j < 391) ? bsum[j] : 0;
    s += v[k];
  }
  int x = s;
#pragma unroll
  for (int o = 1; o < 64; o <<= 1) {
    int y = __shfl_up(x, o, 64);
    if (l >= o) x += y;
  }
  int excl = x - s;
#pragma unroll
  for (int k = 0; k < 7; ++k) {
    int j = base + k;
    if (j < 391) bbase[j] = excl;
    excl += v[k];
  }
  if (l == 63) offs[NNODES] = x;
}

__global__ void k_offs(const int* __restrict__ cnt, const int* __restrict__ bbase,
                       int* __restrict__ offs, int* __restrict__ cursor) {
  __shared__ int sw[4], swo[4];
  int t = threadIdx.x;
  int i = blockIdx.x * 256 + t;
  int v = (i < NNODES) ? cnt[i] : 0;
  int x = v;
#pragma unroll
  for (int o = 1; o < 64; o <<= 1) {
    int y = __shfl_up(x, o, 64);
    if ((t & 63) >= o) x += y;
  }
  if ((t & 63) == 63) sw[t >> 6] = x;
  __syncthreads();
  if (t == 0) {
    int a = 0;
#pragma unroll
    for (int w = 0; w < 4; ++w) { swo[w] = a; a += sw[w]; }
  }
  __syncthreads();
  if (i < NNODES) {
    int e = bbase[blockIdx.x] + swo[t >> 6] + x - v;
    offs[i] = e;
    cursor[i] = e;
  }
}

// fill CSR: src only (coefs come from dinv-prescaling)
__global__ void k_fill(const int* __restrict__ ei, int* __restrict__ cursor,
                       int* __restrict__ csr_src, const int* __restrict__ flags) {
  int e = blockIdx.x * blockDim.x + threadIdx.x;
  if (e < NEDGES) {
    int i64 = flags[1];
    int s = edge_at(ei, e, i64), d = edge_at(ei, NEDGES + e, i64);
    if ((unsigned)s < NNODES && (unsigned)d < NNODES) {
      int p = atomicAdd(&cursor[d], 1);
      if ((unsigned)p < NEDGES) csr_src[p] = s;
    }
  }
}

// ---------- plane-partitioned aggregation ----------
// Input IP: [NP][N][16] bf16 planes. One 16-col plane = 3.2 MB -> fits one
// XCD's 4 MiB L2. Plane pinned to XCD via blockIdx%8 (NP=16: two phases;
// NP=3: XCD groups {0,3,6},{1,4,7},{2,5}).
// Wave = 1 node x 1 plane: 8 lane-groups of 8 process 8 edges/iter, each lane
// holds 2 columns (uint gather). GDINV: gather dinv[src] (raw input planes);
// else input is prescaled by dinv. Output: dinv[v]*(sum + self), bf16 planes
// or f32 planes (OUTF32, feeds the log-softmax pass).
template <int NP, bool GDINV, bool OUTF32>
__global__ __launch_bounds__(256) void k_aggp(
    const unsigned short* __restrict__ IP, unsigned short* __restrict__ OPu,
    const int* __restrict__ offs, const int* __restrict__ csr_src,
    const float* __restrict__ dinv) {
  int b = blockIdx.x;
  int plane, j0, gsz, gidx;
  if (NP == 8) {
    plane = b & 7; j0 = b >> 3; gsz = 1; gidx = 0;
  } else if (NP == 16) {
    const int half = 8 * 2500;
    int ph = (b >= half) ? 1 : 0;
    int bb = b - ph * half;
    plane = (bb & 7) + (ph << 3); j0 = bb >> 3; gsz = 1; gidx = 0;
  } else {  // NP == 3
    int xcd = b & 7;
    plane = xcd % 3;
    gidx = xcd / 3;
    gsz = (plane < 2) ? 3 : 2;
    j0 = b >> 3;
  }
  const int JSTEP = (NP == 3) ? 1250 : 2500;
  const int wvi = threadIdx.x >> 6;
  const int lane = threadIdx.x & 63;
  const int grp = lane >> 3, cl = lane & 7;
  const unsigned short* ip = IP + (size_t)plane * PLANE_ELT;

  for (int j = j0;; j += JSTEP) {
    int nblk = j * gsz + gidx;
    if (nblk >= 25000) break;
    int v = nblk * 4 + wvi;
    float dv = dinv[v];
    unsigned us = *(const unsigned*)(ip + (size_t)v * 16 + (cl << 1));
    float sc = GDINV ? dv : 1.f;
    float acc0 = (grp == 0) ? sc * bf2f(us & 0xffffu) : 0.f;
    float acc1 = (grp == 0) ? sc * bf2f(us >> 16) : 0.f;
    int b0 = offs[v];
    int deg = offs[v + 1] - b0;
    int i = 0;
    for (; i + 16 <= deg; i += 16) {
      int s0 = __builtin_nontemporal_load(csr_src + b0 + i + grp);
      int s1 = __builtin_nontemporal_load(csr_src + b0 + i + 8 + grp);
      unsigned u0 = *(const unsigned*)(ip + (size_t)s0 * 16 + (cl << 1));
      unsigned u1 = *(const unsigned*)(ip + (size_t)s1 * 16 + (cl << 1));
      float w0 = GDINV ? dinv[s0] : 1.f;
      float w1 = GDINV ? dinv[s1] : 1.f;
      acc0 += w0 * bf2f(u0 & 0xffffu);
      acc1 += w0 * bf2f(u0 >> 16);
      acc0 += w1 * bf2f(u1 & 0xffffu);
      acc1 += w1 * bf2f(u1 >> 16);
    }
    for (; i < deg; i += 8) {
      int e = i + grp;
      int ee = (e < deg) ? e : (deg - 1);
      int src = __builtin_nontemporal_load(csr_src + b0 + ee);
      float w = (e < deg) ? (GDINV ? dinv[src] : 1.f) : 0.f;
      unsigned u = *(const unsigned*)(ip + (size_t)src * 16 + (cl << 1));
      acc0 += w * bf2f(u & 0xffffu);
      acc1 += w * bf2f(u >> 16);
    }
#pragma unroll
    for (int o = 8; o < 64; o <<= 1) {
      acc0 += __shfl_xor(acc0, o, 64);
      acc1 += __shfl_xor(acc1, o, 64);
    }
    if (grp == 0) {
      if (OUTF32) {
        float* outf = (float*)OPu;
        f32x2 val;
        val.x = dv * acc0;
        val.y = dv * acc1;
        __builtin_nontemporal_store(
            val, (f32x2*)(outf + (size_t)plane * PLANE_ELT + (size_t)v * 16 + (cl << 1)));
      } else {
        unsigned r = (unsigned)f2bf(dv * acc0) | ((unsigned)f2bf(dv * acc1) << 16);
        __builtin_nontemporal_store(
            r, (unsigned*)(OPu + (size_t)plane * PLANE_ELT + (size_t)v * 16 + (cl << 1)));
      }
    }
  }
}

// ---------- layer-3 bias + log_softmax over 40 cols (f32 planes in) ----------
__global__ __launch_bounds__(256) void k_ls40(
    const float* __restrict__ O40f, const unsigned short* __restrict__ bias,
    float* __restrict__ outp) {
  int t = threadIdx.x;
  int wvi = t >> 6, lane = t & 63;
  int half = lane >> 5, lact = lane & 31;
  int v = blockIdx.x * 8 + wvi * 2 + half;
  if (v >= NNODES) return;
  bool act = lact < 20;
  int plane = lact >> 3, cl = lact & 7;
  int col0 = plane * 16 + cl * 2;
  float a0 = 0.f, a1 = 0.f;
  if (act) {
    f32x2 u = *(const f32x2*)(O40f + (size_t)plane * PLANE_ELT + (size_t)v * 16 + (cl << 1));
    a0 = u.x + bf2f((unsigned)bias[col0]);
    a1 = u.y + bf2f((unsigned)bias[col0 + 1]);
  }
  float m = act ? fmaxf(a0, a1) : -1e30f;
#pragma unroll
  for (int o = 16; o > 0; o >>= 1) m = fmaxf(m, __shfl_xor(m, o, 32));
  float ss = act ? (expf(a0 - m) + expf(a1 - m)) : 0.f;
#pragma unroll
  for (int o = 16; o > 0; o >>= 1) ss += __shfl_xor(ss, o, 32);
  float ls = logf(ss) + m;
  if (act) {
    float2 o2;
    o2.x = a0 - ls;
    o2.y = a1 - ls;
    *(float2*)(outp + (size_t)v * 160 + col0) = o2;
  }
}

// ---------- MFMA continue GEMM: out = relu(A@W + b) [* dinv if SCALE] ----------
// A in plane layout [K/16][N][16]; out written in plane layout too.
template <int K, bool SCALE>
__global__ __launch_bounds__(256) void k_mlp_mfma(
    const unsigned short* __restrict__ A, const unsigned short* __restrict__ WT,
    const unsigned short* __restrict__ bias, unsigned short* __restrict__ out,
    const float* __restrict__ dinv) {
  __shared__ short As[128 * 40];
  __shared__ short Bs[128 * 40];
  const int t = threadIdx.x;
  const int lane = t & 63, wvq = t >> 6;
  const int m0 = blockIdx.x * 128;
  const int c0 = blockIdx.y * 128;
  const int mw = (wvq >> 1) * 64, nw = (wvq & 1) * 64;
  const int lr = lane & 15, lq = lane >> 4;

  f32x4 acc[4][4];
#pragma unroll
  for (int i = 0; i < 4; ++i)
#pragma unroll
    for (int j = 0; j < 4; ++j) acc[i][j] = (f32x4)0.f;

  for (int kc = 0; kc < K; kc += 32) {
    __syncthreads();
#pragma unroll
    for (int it = 0; it < 2; ++it) {
      int idx = t + it * 256;
      int row = idx >> 2, seg = idx & 3;
      int cc = kc + seg * 8;
      uint4 u = make_uint4(0, 0, 0, 0);
      int gr = m0 + row;
      if (gr < NNODES)
        u = *(const uint4*)(A + (size_t)(cc >> 4) * PLANE_ELT + (size_t)gr * 16 + (cc & 15));
      *(uint4*)&As[row * 40 + seg * 8] = u;
      uint4 w = *(const uint4*)(WT + (size_t)(c0 + row) * K + cc);
      *(uint4*)&Bs[row * 40 + seg * 8] = w;
    }
    __syncthreads();
    bf16x8 af[4], bfr[4];
#pragma unroll
    for (int i = 0; i < 4; ++i)
      af[i] = *(const bf16x8*)&As[(mw + 16 * i + lr) * 40 + lq * 8];
#pragma unroll
    for (int j = 0; j < 4; ++j)
      bfr[j] = *(const bf16x8*)&Bs[(nw + 16 * j + lr) * 40 + lq * 8];
#pragma unroll
    for (int i = 0; i < 4; ++i)
#pragma unroll
      for (int j = 0; j < 4; ++j)
        acc[i][j] = __builtin_amdgcn_mfma_f32_16x16x32_bf16(af[i], bfr[j], acc[i][j], 0, 0, 0);
  }

  float bv[4];
#pragma unroll
  for (int j = 0; j < 4; ++j) bv[j] = bf2f((unsigned)bias[c0 + nw + 16 * j + lr]);
#pragma unroll
  for (int i = 0; i < 4; ++i) {
    int rbase = m0 + mw + 16 * i + lq * 4;
#pragma unroll
    for (int r = 0; r < 4; ++r) {
      int row = rbase + r;
      if (row < NNODES) {
        float s = SCALE ? dinv[row] : 1.f;
#pragma unroll
        for (int j = 0; j < 4; ++j) {
          int col = c0 + nw + 16 * j + lr;
          float vv = fmaxf(acc[i][j][r] + bv[j], 0.f) * s;
          out[(size_t)(col >> 4) * PLANE_ELT + (size_t)row * 16 + (col & 15)] = f2bf(vv);
        }
      }
    }
  }
}

// ---------- MFMA exit GEMM (+ optional fused log_softmax) ----------
// A in plane layout. SOFTMAX: write f32 log-softmax rows to outp.
// !SOFTMAX: write P = (A@We)*dinv[row] as 3 bf16 planes (cols 40..47 zero).
template <int K, bool SOFTMAX>
__global__ __launch_bounds__(256) void k_exit_mfma(
    const unsigned short* __restrict__ A, const unsigned short* __restrict__ WT,
    const unsigned short* __restrict__ bias, float* __restrict__ outp,
    unsigned short* __restrict__ Pout, const float* __restrict__ dinv) {
  __shared__ short As[256 * 40];
  __shared__ short Bs[48 * 40];
  const int t = threadIdx.x;
  const int lane = t & 63, wvq = t >> 6;
  const int m0 = blockIdx.x * 256;
  const int mw = wvq * 64;
  const int lr = lane & 15, lq = lane >> 4;

  f32x4 acc[4][3];
#pragma unroll
  for (int i = 0; i < 4; ++i)
#pragma unroll
    for (int j = 0; j < 3; ++j) acc[i][j] = (f32x4)0.f;

  for (int kc = 0; kc < K; kc += 32) {
    __syncthreads();
#pragma unroll
    for (int it = 0; it < 4; ++it) {
      int idx = t + it * 256;
      int row = idx >> 2, seg = idx & 3;
      int cc = kc + seg * 8;
      uint4 u = make_uint4(0, 0, 0, 0);
      int gr = m0 + row;
      if (gr < NNODES)
        u = *(const uint4*)(A + (size_t)(cc >> 4) * PLANE_ELT + (size_t)gr * 16 + (cc & 15));
      *(uint4*)&As[row * 40 + seg * 8] = u;
    }
    if (t < 192) {
      int row = t >> 2, seg = t & 3;
      uint4 w = *(const uint4*)(WT + (size_t)row * K + kc + seg * 8);
      *(uint4*)&Bs[row * 40 + seg * 8] = w;
    }
    __syncthreads();
    bf16x8 af[4], bfr[3];
#pragma unroll
    for (int i = 0; i < 4; ++i)
      af[i] = *(const bf16x8*)&As[(mw + 16 * i + lr) * 40 + lq * 8];
#pragma unroll
    for (int j = 0; j < 3; ++j)
      bfr[j] = *(const bf16x8*)&Bs[(16 * j + lr) * 40 + lq * 8];
#pragma unroll
    for (int i = 0; i < 4; ++i)
#pragma unroll
      for (int j = 0; j < 3; ++j)
        acc[i][j] = __builtin_amdgcn_mfma_f32_16x16x32_bf16(af[i], bfr[j], acc[i][j], 0, 0, 0);
  }

  if (SOFTMAX) {
    float bv0 = bf2f((unsigned)bias[lr]);
    float bv1 = bf2f((unsigned)bias[16 + lr]);
    float bv2 = (lr < 8) ? bf2f((unsigned)bias[32 + lr]) : 0.f;
#pragma unroll
    for (int i = 0; i < 4; ++i) {
#pragma unroll
      for (int r = 0; r < 4; ++r) {
        int row = m0 + mw + 16 * i + lq * 4 + r;
        float v0 = acc[i][0][r] + bv0;
        float v1 = acc[i][1][r] + bv1;
        float v2 = (lr < 8) ? (acc[i][2][r] + bv2) : -1e30f;
        float m = fmaxf(fmaxf(v0, v1), v2);
#pragma unroll
        for (int o = 8; o > 0; o >>= 1) m = fmaxf(m, __shfl_xor(m, o, 16));
        float ss = expf(v0 - m) + expf(v1 - m) + ((lr < 8) ? expf(v2 - m) : 0.f);
#pragma unroll
        for (int o = 8; o > 0; o >>= 1) ss += __shfl_xor(ss, o, 16);
        float ls = logf(ss) + m;
        if (row < NNODES) {
          outp[(size_t)row * 160 + lr] = v0 - ls;
          outp[(size_t)row * 160 + 16 + lr] = v1 - ls;
          if (lr < 8) outp[(size_t)row * 160 + 32 + lr] = v2 - ls;
        }
      }
    }
  } else {
#pragma unroll
    for (int i = 0; i < 4; ++i) {
#pragma unroll
      for (int r = 0; r < 4; ++r) {
        int row = m0 + mw + 16 * i + lq * 4 + r;
        if (row < NNODES) {
          float s = dinv[row];
          Pout[(size_t)row * 16 + lr] = f2bf(acc[i][0][r] * s);
          Pout[PLANE_ELT + (size_t)row * 16 + lr] = f2bf(acc[i][1][r] * s);
          Pout[2 * PLANE_ELT + (size_t)row * 16 + lr] =
              (lr < 8) ? f2bf(acc[i][2][r] * s) : (unsigned short)0;
        }
      }
    }
  }
}

// ---------- launch ----------
extern "C" void kernel_launch(void* const* d_in, const int* in_sizes, int n_in,
                              void* d_out, int out_size, void* d_ws, size_t ws_size,
                              hipStream_t stream) {
  const void* x_raw   = d_in[0];
  const int* ei       = (const int*)d_in[1];
  float* out          = (float*)d_out;

  char* ws = (char*)d_ws;
  int*   flags    = (int*)(ws + 0);
  int*   bsum     = (int*)(ws + 1024);
  int*   bbase    = (int*)(ws + 2816);
  int*   cnt      = (int*)(ws + 8192);
  int*   offs     = (int*)(ws + 524288);
  int*   cursor   = (int*)(ws + 1048576);
  float* dinv     = (float*)(ws + 1572864);
  int*   csr_src  = (int*)(ws + 2097152);                  // 6.4 MB src-only CSR
  unsigned short* xpl = (unsigned short*)(ws + 16777216);  // x planes 25.6MB; later P planes
  unsigned short* wb  = (unsigned short*)(ws + 45088768);  // weights
  unsigned short* hAp = (unsigned short*)(ws + 48234496);  // up to 16 planes (51.2MB); later O40f
  unsigned short* hBp = (unsigned short*)(ws + 100663296); // 16 planes (51.2MB)
  unsigned short* Pp  = xpl;                               // 3 planes, 9.6MB
  float* O40f = (float*)(ws + 48234496);                   // 3 f32 planes, 19.2MB

  unsigned short* Wc0 = wb + 0;
  unsigned short* bc0 = wb + 32768;
  unsigned short* Wc1 = wb + 33024;
  unsigned short* bc1 = wb + 98560;
  unsigned short* We0 = wb + 98816;
  unsigned short* be0 = wb + 103936;
  unsigned short* We1 = wb + 103976;
  unsigned short* be1 = wb + 109096;
  unsigned short* We2 = wb + 109136;
  unsigned short* be2 = wb + 119376;
  unsigned short* We3 = wb + 119416;
  unsigned short* be3 = wb + 129656;
  unsigned short* WTc0  = wb + 131072;  // 256 x 128
  unsigned short* WTc1  = wb + 163840;  // 256 x 256
  unsigned short* WT40e0 = wb + 229376; // 48 x 128
  unsigned short* WT40e1 = wb + 235520; // 48 x 128
  unsigned short* WT40e2 = wb + 241664; // 48 x 256
  unsigned short* WT40e3 = wb + 253952; // 48 x 256

  dim3 B(256);
  k_probe<<<dim3(1), B, 0, stream>>>((const unsigned*)x_raw, ei, flags);
  k_zero<<<dim3(391), B, 0, stream>>>(cnt, NNODES);

  CvtParams p;
  const int srcIdx[13] = {0, 2, 3, 4, 5, 8, 9, 10, 11, 12, 13, 14, 15};
  unsigned short* dsts[13] = {xpl, Wc0, bc0, Wc1, bc1, We0, be0, We1, be1, We2, be2, We3, be3};
  const int ns[13] = {NNODES * 128, 128 * 256, 256, 256 * 256, 256,
                      128 * 40, 40, 128 * 40, 40, 256 * 40, 40, 256 * 40, 40};
  for (int i = 0; i < 13; ++i) { p.src[i] = d_in[srcIdx[i]]; p.dst[i] = dsts[i]; p.n[i] = ns[i]; }
  k_cvt<<<dim3(1024, 13), B, 0, stream>>>(p, flags);
  k_transpose<<<dim3(128), B, 0, stream>>>(Wc0, WTc0, 128);
  k_transpose<<<dim3(256), B, 0, stream>>>(Wc1, WTc1, 256);
  k_transpose40<128><<<dim3(24), B, 0, stream>>>(We0, WT40e0);
  k_transpose40<128><<<dim3(24), B, 0, stream>>>(We1, WT40e1);
  k_transpose40<256><<<dim3(48), B, 0, stream>>>(We2, WT40e2);
  k_transpose40<256><<<dim3(48), B, 0, stream>>>(We3, WT40e3);

  k_count<<<dim3(6250), B, 0, stream>>>(ei, cnt, flags);
  k_dinv<<<dim3(391), B, 0, stream>>>(cnt, dinv);
  k_psum<<<dim3(391), B, 0, stream>>>(cnt, bsum);
  k_bscan<<<dim3(1), dim3(64), 0, stream>>>(bsum, bbase, offs);
  k_offs<<<dim3(391), B, 0, stream>>>(cnt, bbase, offs, cursor);
  k_fill<<<dim3(6250), B, 0, stream>>>(ei, cursor, csr_src, flags);

  // layer 0: on x (planes, raw)
  k_exit_mfma<128, true><<<dim3(391), B, 0, stream>>>(xpl, WT40e0, be0, out + 0 * 40, nullptr, dinv);
  // h1 = agg(x): raw planes in, dinv[src] gathered
  k_aggp<8, true, false><<<dim3(20000), B, 0, stream>>>(xpl, hAp, offs, csr_src, dinv);
  k_exit_mfma<128, true><<<dim3(391), B, 0, stream>>>(hAp, WT40e1, be1, out + 1 * 40, nullptr, dinv);
  // hB = relu(h1 Wc0 + bc0) * dinv  (prescaled for agg)
  k_mlp_mfma<128, true><<<dim3(782, 2), B, 0, stream>>>(hAp, WTc0, bc0, hBp, dinv);
  // h2 = agg(hB): prescaled planes in
  k_aggp<16, false, false><<<dim3(40000), B, 0, stream>>>(hBp, hAp, offs, csr_src, dinv);
  k_exit_mfma<256, true><<<dim3(391), B, 0, stream>>>(hAp, WT40e2, be2, out + 2 * 40, nullptr, dinv);
  k_mlp_mfma<256, false><<<dim3(782, 2), B, 0, stream>>>(hAp, WTc1, bc1, hBp, nullptr);
  // layer 3 push-through: P = (hc2 @ We3) * dinv, 3 planes
  k_exit_mfma<256, false><<<dim3(391), B, 0, stream>>>(hBp, WT40e3, nullptr, nullptr, Pp, dinv);
  k_aggp<3, false, true><<<dim3(10000), B, 0, stream>>>(Pp, (unsigned short*)O40f, offs, csr_src, dinv);
  k_ls40<<<dim3(12500), B, 0, stream>>>(O40f, be3, out + 3 * 40);
}

// Round 2
// 813.574 us; speedup vs baseline: 1.6639x; 1.6639x over previous
//
#include <hip/hip_runtime.h>

#define NNODES 100000
#define NEDGES 1600000

typedef __attribute__((ext_vector_type(8))) short bf16x8;
typedef __attribute__((ext_vector_type(4))) float f32x4;

// ---------- bf16 helpers ----------
__device__ __forceinline__ float bf2f(unsigned v) {
  union { unsigned u; float f; } x; x.u = v << 16; return x.f;
}
__device__ __forceinline__ unsigned short f2bf(float f) {
  union { float f; unsigned u; } x; x.f = f;
  unsigned r = x.u + 0x7fffu + ((x.u >> 16) & 1u);
  return (unsigned short)(r >> 16);
}

// ---------- dtype probing ----------
__global__ void k_probe(const unsigned* __restrict__ xw, const int* __restrict__ ei,
                        int* __restrict__ flags) {
  __shared__ int cF, cI;
  if (threadIdx.x == 0) { cF = 0; cI = 0; }
  __syncthreads();
  int t = threadIdx.x;
  int hf = 0;
  for (int i = t; i < 2048; i += 256) {
    unsigned lo = xw[i] & 0xffffu;
    unsigned e = (lo >> 7) & 0xffu;
    if (e >= 0xC0u) hf++;
  }
  atomicAdd(&cF, hf);
  int hi = 0;
  if (ei[2 * t + 1] != 0) hi++;
  atomicAdd(&cI, hi);
  __syncthreads();
  if (threadIdx.x == 0) {
    flags[0] = (cF > 32) ? 1 : 0;
    flags[1] = (cI < 16) ? 1 : 0;
  }
}

__device__ __forceinline__ int edge_at(const int* __restrict__ ei, int j, int i64) {
  return i64 ? ei[2 * j] : ei[j];
}

// ---------- canonicalize float arrays to bf16 ----------
struct CvtParams {
  const void* src[13];
  unsigned short* dst[13];
  int n[13];
};

__global__ void k_cvt(CvtParams p, const int* __restrict__ flags) {
  int a = blockIdx.y;
  int n = p.n[a];
  int f32 = flags[0];
  const float* sf = (const float*)p.src[a];
  const unsigned short* sb = (const unsigned short*)p.src[a];
  unsigned short* d = p.dst[a];
  for (int i = blockIdx.x * blockDim.x + threadIdx.x; i < n; i += gridDim.x * blockDim.x) {
    d[i] = f32 ? f2bf(sf[i]) : sb[i];
  }
}

// transpose W[K,256] -> WT[256,K]
__global__ void k_transpose(const unsigned short* __restrict__ W,
                            unsigned short* __restrict__ WT, int K) {
  int idx = blockIdx.x * 256 + threadIdx.x;
  if (idx < K * 256) {
    int k = idx >> 8, c = idx & 255;
    WT[c * K + k] = W[idx];
  }
}

// transpose W[K,40] -> WT[48,K], rows 40..47 zero
template <int K>
__global__ void k_transpose40(const unsigned short* __restrict__ W,
                              unsigned short* __restrict__ WT) {
  int idx = blockIdx.x * 256 + threadIdx.x;
  if (idx < 48 * K) {
    int c = idx / K, k = idx % K;
    WT[idx] = (c < 40) ? W[k * 40 + c] : (unsigned short)0;
  }
}

__global__ void k_zero(int* __restrict__ p, int n) {
  int v = blockIdx.x * blockDim.x + threadIdx.x;
  if (v < n) p[v] = 0;
}

// ---------- graph preprocessing ----------
__global__ void k_count(const int* __restrict__ ei, int* __restrict__ cnt,
                        const int* __restrict__ flags) {
  int e = blockIdx.x * blockDim.x + threadIdx.x;
  if (e < NEDGES) {
    int i64 = flags[1];
    int d = edge_at(ei, NEDGES + e, i64);
    if ((unsigned)d < NNODES) atomicAdd(&cnt[d], 1);
  }
}

__global__ void k_dinv(const int* __restrict__ cnt, float* __restrict__ dinv) {
  int v = blockIdx.x * blockDim.x + threadIdx.x;
  if (v < NNODES) dinv[v] = rsqrtf((float)cnt[v] + 1.0f);
}

// ---------- parallel scan ----------
__global__ void k_psum(const int* __restrict__ cnt, int* __restrict__ bsum) {
  __shared__ int sw[4];
  int t = threadIdx.x;
  int i = blockIdx.x * 256 + t;
  int v = (i < NNODES) ? cnt[i] : 0;
  int x = v;
#pragma unroll
  for (int o = 1; o < 64; o <<= 1) {
    int y = __shfl_up(x, o, 64);
    if ((t & 63) >= o) x += y;
  }
  if ((t & 63) == 63) sw[t >> 6] = x;
  __syncthreads();
  if (t == 0) bsum[blockIdx.x] = sw[0] + sw[1] + sw[2] + sw[3];
}

__global__ void k_bscan(const int* __restrict__ bsum, int* __restrict__ bbase,
                        int* __restrict__ offs) {
  int l = threadIdx.x;
  int base = l * 7;
  int v[7];
  int s = 0;
#pragma unroll
  for (int k = 0; k < 7; ++k) {
    int j = base + k;
    v[k] = (j < 391) ? bsum[j] : 0;
    s += v[k];
  }
  int x = s;
#pragma unroll
  for (int o = 1; o < 64; o <<= 1) {
    int y = __shfl_up(x, o, 64);
    if (l >= o) x += y;
  }
  int excl = x - s;
#pragma unroll
  for (int k = 0; k < 7; ++k) {
    int j = base + k;
    if (j < 391) bbase[j] = excl;
    excl += v[k];
  }
  if (l == 63) offs[NNODES] = x;
}

__global__ void k_offs(const int* __restrict__ cnt, const int* __restrict__ bbase,
                       int* __restrict__ offs, int* __restrict__ cursor) {
  __shared__ int sw[4], swo[4];
  int t = threadIdx.x;
  int i = blockIdx.x * 256 + t;
  int v = (i < NNODES) ? cnt[i] : 0;
  int x = v;
#pragma unroll
  for (int o = 1; o < 64; o <<= 1) {
    int y = __shfl_up(x, o, 64);
    if ((t & 63) >= o) x += y;
  }
  if ((t & 63) == 63) sw[t >> 6] = x;
  __syncthreads();
  if (t == 0) {
    int a = 0;
#pragma unroll
    for (int w = 0; w < 4; ++w) { swo[w] = a; a += sw[w]; }
  }
  __syncthreads();
  if (i < NNODES) {
    int e = bbase[blockIdx.x] + swo[t >> 6] + x - v;
    offs[i] = e;
    cursor[i] = e;
  }
}

// fill CSR: src only (coefs come from dinv-prescaling)
__global__ void k_fill(const int* __restrict__ ei, int* __restrict__ cursor,
                       int* __restrict__ csr_src, const int* __restrict__ flags) {
  int e = blockIdx.x * blockDim.x + threadIdx.x;
  if (e < NEDGES) {
    int i64 = flags[1];
    int s = edge_at(ei, e, i64), d = edge_at(ei, NEDGES + e, i64);
    if ((unsigned)s < NNODES && (unsigned)d < NNODES) {
      int p = atomicAdd(&cursor[d], 1);
      if ((unsigned)p < NEDGES) csr_src[p] = s;
    }
  }
}

__device__ __forceinline__ void acc8(float (&acc)[8], uint4 u, float w) {
  acc[0] += w * bf2f(u.x & 0xffffu);
  acc[1] += w * bf2f(u.x >> 16);
  acc[2] += w * bf2f(u.y & 0xffffu);
  acc[3] += w * bf2f(u.y >> 16);
  acc[4] += w * bf2f(u.z & 0xffffu);
  acc[5] += w * bf2f(u.z >> 16);
  acc[6] += w * bf2f(u.w & 0xffffu);
  acc[7] += w * bf2f(u.w >> 16);
}

// ---------- aggregation: wave per node, 16 B/lane multi-row gathers ----------
// D=128: 16 lanes/row, 4 rows/instr; D=256: 32 lanes/row, 2 rows/instr.
// 4 gather instrs per batch, clamped-index padding (weight 0) -> no tail loop.
// GDINV: gather dinv[src] (raw input); else input rows prescaled by dinv[src].
// out[v] = dinv[v] * (sum_edges + self'), self' handled by group 0 only.
template <int D, bool GDINV>
__global__ __launch_bounds__(256) void k_agg(
    const unsigned short* __restrict__ hin, unsigned short* __restrict__ hout,
    const int* __restrict__ offs, const int* __restrict__ csr_src,
    const float* __restrict__ dinv) {
  constexpr int LPR = D / 8;    // lanes per row (16 B each)
  constexpr int R = 64 / LPR;   // rows per gather instr
  const int lane = threadIdx.x & 63;
  const int g = lane / LPR;     // row-group
  const int l = lane % LPR;     // lane within row
  const int w0 = (blockIdx.x * 256 + threadIdx.x) >> 6;
  const int nw = gridDim.x * 4;

  for (int v = w0; v < NNODES; v += nw) {
    float dv = dinv[v];
    const size_t vbase = (size_t)v * D + l * 8;
    uint4 su = *(const uint4*)(hin + vbase);
    float acc[8];
#pragma unroll
    for (int k = 0; k < 8; ++k) acc[k] = 0.f;
    float ssc = (g == 0) ? (GDINV ? dv : 1.f) : 0.f;
    acc8(acc, su, ssc);

    int b0 = offs[v];
    int n = offs[v + 1] - b0;
    if (n > 0) {
      for (int i = 0; i < n; i += 4 * R) {
        int s[4];
        float wg[4];
#pragma unroll
        for (int j = 0; j < 4; ++j) {
          int ei = i + j * R + g;
          int ec = (ei < n) ? ei : (n - 1);
          s[j] = csr_src[b0 + ec];
          wg[j] = (ei < n) ? (GDINV ? dinv[s[j]] : 1.f) : 0.f;
        }
        uint4 gu[4];
#pragma unroll
        for (int j = 0; j < 4; ++j)
          gu[j] = *(const uint4*)(hin + (size_t)s[j] * D + l * 8);
#pragma unroll
        for (int j = 0; j < 4; ++j) acc8(acc, gu[j], wg[j]);
      }
    }
#pragma unroll
    for (int k = 0; k < 8; ++k) {
#pragma unroll
      for (int o = LPR; o < 64; o <<= 1) acc[k] += __shfl_xor(acc[k], o, 64);
    }
    if (g == 0) {
      uint4 ov;
      ov.x = (unsigned)f2bf(dv * acc[0]) | ((unsigned)f2bf(dv * acc[1]) << 16);
      ov.y = (unsigned)f2bf(dv * acc[2]) | ((unsigned)f2bf(dv * acc[3]) << 16);
      ov.z = (unsigned)f2bf(dv * acc[4]) | ((unsigned)f2bf(dv * acc[5]) << 16);
      ov.w = (unsigned)f2bf(dv * acc[6]) | ((unsigned)f2bf(dv * acc[7]) << 16);
      *(uint4*)(hout + vbase) = ov;
    }
  }
}

// ---------- width-40 aggregation + bias + log_softmax (layer 3) ----------
// P prescaled by dinv[row]. 2 row-groups of 32 lanes (lanes 0..19 active),
// 4 gather instrs x 2 rows = 8 edges per batch, clamped padding.
__global__ __launch_bounds__(256) void k_agg40(
    const unsigned short* __restrict__ P, const int* __restrict__ offs,
    const int* __restrict__ csr_src, const float* __restrict__ dinv,
    const unsigned short* __restrict__ bias, float* __restrict__ outp) {
  const int lane = threadIdx.x & 63;
  const int g = lane >> 5, l = lane & 31;
  const bool act = l < 20;
  const int w0 = (blockIdx.x * 256 + threadIdx.x) >> 6;
  const int nw = gridDim.x * 4;

  for (int v = w0; v < NNODES; v += nw) {
    float dv = dinv[v];
    float a0 = 0.f, a1 = 0.f;
    if (act && g == 0) {
      unsigned su = *(const unsigned*)(P + (size_t)v * 40 + l * 2);
      a0 = bf2f(su & 0xffffu);
      a1 = bf2f(su >> 16);
    }
    int b0 = offs[v];
    int n = offs[v + 1] - b0;
    if (n > 0) {
      for (int i = 0; i < n; i += 8) {
        int s[4];
        float wg[4];
#pragma unroll
        for (int j = 0; j < 4; ++j) {
          int ei = i + j * 2 + g;
          int ec = (ei < n) ? ei : (n - 1);
          s[j] = csr_src[b0 + ec];
          wg[j] = (ei < n) ? 1.f : 0.f;
        }
        unsigned gu[4];
#pragma unroll
        for (int j = 0; j < 4; ++j)
          gu[j] = act ? *(const unsigned*)(P + (size_t)s[j] * 40 + l * 2) : 0u;
#pragma unroll
        for (int j = 0; j < 4; ++j) {
          a0 += wg[j] * bf2f(gu[j] & 0xffffu);
          a1 += wg[j] * bf2f(gu[j] >> 16);
        }
      }
    }
    // combine the two row-groups
    a0 += __shfl_xor(a0, 32, 64);
    a1 += __shfl_xor(a1, 32, 64);
    // bias + log_softmax over 40 cols (each 32-lane half has full sums)
    if (act) {
      a0 = dv * a0 + bf2f((unsigned)bias[l * 2]);
      a1 = dv * a1 + bf2f((unsigned)bias[l * 2 + 1]);
    }
    float m = act ? fmaxf(a0, a1) : -1e30f;
#pragma unroll
    for (int o = 16; o > 0; o >>= 1) m = fmaxf(m, __shfl_xor(m, o, 32));
    float ss = act ? (expf(a0 - m) + expf(a1 - m)) : 0.f;
#pragma unroll
    for (int o = 16; o > 0; o >>= 1) ss += __shfl_xor(ss, o, 32);
    float ls = logf(ss) + m;
    if (act && g == 0) {
      float2 o2;
      o2.x = a0 - ls;
      o2.y = a1 - ls;
      *(float2*)(outp + (size_t)v * 160 + l * 2) = o2;
    }
  }
}

// ---------- MFMA continue GEMM: out = relu(A[N,K] @ W[K,256] + b) [* dinv] ----------
template <int K, bool SCALE>
__global__ __launch_bounds__(256) void k_mlp_mfma(
    const unsigned short* __restrict__ A, const unsigned short* __restrict__ WT,
    const unsigned short* __restrict__ bias, unsigned short* __restrict__ out,
    const float* __restrict__ dinv) {
  __shared__ short As[128 * 40];
  __shared__ short Bs[128 * 40];
  const int t = threadIdx.x;
  const int lane = t & 63, wv = t >> 6;
  const int m0 = blockIdx.x * 128;
  const int c0 = blockIdx.y * 128;
  const int mw = (wv >> 1) * 64, nw = (wv & 1) * 64;
  const int lr = lane & 15, lq = lane >> 4;

  f32x4 acc[4][4];
#pragma unroll
  for (int i = 0; i < 4; ++i)
#pragma unroll
    for (int j = 0; j < 4; ++j) acc[i][j] = (f32x4)0.f;

  for (int kc = 0; kc < K; kc += 32) {
    __syncthreads();
#pragma unroll
    for (int it = 0; it < 2; ++it) {
      int idx = t + it * 256;
      int row = idx >> 2, seg = idx & 3;
      uint4 u = make_uint4(0, 0, 0, 0);
      int gr = m0 + row;
      if (gr < NNODES) u = *(const uint4*)(A + (size_t)gr * K + kc + seg * 8);
      *(uint4*)&As[row * 40 + seg * 8] = u;
      uint4 v = *(const uint4*)(WT + (size_t)(c0 + row) * K + kc + seg * 8);
      *(uint4*)&Bs[row * 40 + seg * 8] = v;
    }
    __syncthreads();
    bf16x8 af[4], bfr[4];
#pragma unroll
    for (int i = 0; i < 4; ++i)
      af[i] = *(const bf16x8*)&As[(mw + 16 * i + lr) * 40 + lq * 8];
#pragma unroll
    for (int j = 0; j < 4; ++j)
      bfr[j] = *(const bf16x8*)&Bs[(nw + 16 * j + lr) * 40 + lq * 8];
#pragma unroll
    for (int i = 0; i < 4; ++i)
#pragma unroll
      for (int j = 0; j < 4; ++j)
        acc[i][j] = __builtin_amdgcn_mfma_f32_16x16x32_bf16(af[i], bfr[j], acc[i][j], 0, 0, 0);
  }

  float bv[4];
#pragma unroll
  for (int j = 0; j < 4; ++j) bv[j] = bf2f((unsigned)bias[c0 + nw + 16 * j + lr]);
#pragma unroll
  for (int i = 0; i < 4; ++i) {
    int rbase = m0 + mw + 16 * i + lq * 4;
#pragma unroll
    for (int r = 0; r < 4; ++r) {
      int row = rbase + r;
      if (row < NNODES) {
        float s = SCALE ? dinv[row] : 1.f;
#pragma unroll
        for (int j = 0; j < 4; ++j) {
          int col = c0 + nw + 16 * j + lr;
          float v = fmaxf(acc[i][j][r] + bv[j], 0.f) * s;
          out[(size_t)row * 256 + col] = f2bf(v);
        }
      }
    }
  }
}

// ---------- MFMA exit GEMM (+ optional fused log_softmax) ----------
// !SOFTMAX: writes P = (A@We)*dinv[row], row-major [N][40] bf16.
template <int K, bool SOFTMAX>
__global__ __launch_bounds__(256) void k_exit_mfma(
    const unsigned short* __restrict__ A, const unsigned short* __restrict__ WT,
    const unsigned short* __restrict__ bias, float* __restrict__ outp,
    unsigned short* __restrict__ Pout, const float* __restrict__ dinv) {
  __shared__ short As[256 * 40];
  __shared__ short Bs[48 * 40];
  const int t = threadIdx.x;
  const int lane = t & 63, wv = t >> 6;
  const int m0 = blockIdx.x * 256;
  const int mw = wv * 64;
  const int lr = lane & 15, lq = lane >> 4;

  f32x4 acc[4][3];
#pragma unroll
  for (int i = 0; i < 4; ++i)
#pragma unroll
    for (int j = 0; j < 3; ++j) acc[i][j] = (f32x4)0.f;

  for (int kc = 0; kc < K; kc += 32) {
    __syncthreads();
#pragma unroll
    for (int it = 0; it < 4; ++it) {
      int idx = t + it * 256;
      int row = idx >> 2, seg = idx & 3;
      uint4 u = make_uint4(0, 0, 0, 0);
      int gr = m0 + row;
      if (gr < NNODES) u = *(const uint4*)(A + (size_t)gr * K + kc + seg * 8);
      *(uint4*)&As[row * 40 + seg * 8] = u;
    }
    if (t < 192) {
      int row = t >> 2, seg = t & 3;
      uint4 v = *(const uint4*)(WT + (size_t)row * K + kc + seg * 8);
      *(uint4*)&Bs[row * 40 + seg * 8] = v;
    }
    __syncthreads();
    bf16x8 af[4], bfr[3];
#pragma unroll
    for (int i = 0; i < 4; ++i)
      af[i] = *(const bf16x8*)&As[(mw + 16 * i + lr) * 40 + lq * 8];
#pragma unroll
    for (int j = 0; j < 3; ++j)
      bfr[j] = *(const bf16x8*)&Bs[(16 * j + lr) * 40 + lq * 8];
#pragma unroll
    for (int i = 0; i < 4; ++i)
#pragma unroll
      for (int j = 0; j < 3; ++j)
        acc[i][j] = __builtin_amdgcn_mfma_f32_16x16x32_bf16(af[i], bfr[j], acc[i][j], 0, 0, 0);
  }

  if (SOFTMAX) {
    float bv0 = bf2f((unsigned)bias[lr]);
    float bv1 = bf2f((unsigned)bias[16 + lr]);
    float bv2 = (lr < 8) ? bf2f((unsigned)bias[32 + lr]) : 0.f;
#pragma unroll
    for (int i = 0; i < 4; ++i) {
#pragma unroll
      for (int r = 0; r < 4; ++r) {
        int row = m0 + mw + 16 * i + lq * 4 + r;
        float v0 = acc[i][0][r] + bv0;
        float v1 = acc[i][1][r] + bv1;
        float v2 = (lr < 8) ? (acc[i][2][r] + bv2) : -1e30f;
        float m = fmaxf(fmaxf(v0, v1), v2);
#pragma unroll
        for (int o = 8; o > 0; o >>= 1) m = fmaxf(m, __shfl_xor(m, o, 16));
        float ss = expf(v0 - m) + expf(v1 - m) + ((lr < 8) ? expf(v2 - m) : 0.f);
#pragma unroll
        for (int o = 8; o > 0; o >>= 1) ss += __shfl_xor(ss, o, 16);
        float ls = logf(ss) + m;
        if (row < NNODES) {
          outp[(size_t)row * 160 + lr] = v0 - ls;
          outp[(size_t)row * 160 + 16 + lr] = v1 - ls;
          if (lr < 8) outp[(size_t)row * 160 + 32 + lr] = v2 - ls;
        }
      }
    }
  } else {
#pragma unroll
    for (int i = 0; i < 4; ++i) {
#pragma unroll
      for (int r = 0; r < 4; ++r) {
        int row = m0 + mw + 16 * i + lq * 4 + r;
        if (row < NNODES) {
          float s = dinv[row];
          Pout[(size_t)row * 40 + lr] = f2bf(acc[i][0][r] * s);
          Pout[(size_t)row * 40 + 16 + lr] = f2bf(acc[i][1][r] * s);
          if (lr < 8) Pout[(size_t)row * 40 + 32 + lr] = f2bf(acc[i][2][r] * s);
        }
      }
    }
  }
}

// ---------- launch ----------
extern "C" void kernel_launch(void* const* d_in, const int* in_sizes, int n_in,
                              void* d_out, int out_size, void* d_ws, size_t ws_size,
                              hipStream_t stream) {
  const void* x_raw   = d_in[0];
  const int* ei       = (const int*)d_in[1];
  float* out          = (float*)d_out;

  char* ws = (char*)d_ws;
  int*   flags    = (int*)(ws + 0);
  int*   bsum     = (int*)(ws + 1024);
  int*   bbase    = (int*)(ws + 2816);
  int*   cnt      = (int*)(ws + 8192);
  int*   offs     = (int*)(ws + 524288);
  int*   cursor   = (int*)(ws + 1048576);
  float* dinv     = (float*)(ws + 1572864);
  int*   csr_src  = (int*)(ws + 2097152);                  // 6.4 MB src-only CSR
  unsigned short* xb = (unsigned short*)(ws + 16777216);   // N*128 bf16 (reused as P)
  unsigned short* wb = (unsigned short*)(ws + 45088768);   // weights
  unsigned short* hA = (unsigned short*)(ws + 48234496);   // N*256 bf16
  unsigned short* hB = (unsigned short*)(ws + 100663296);  // N*256 bf16
  unsigned short* P  = xb;

  unsigned short* Wc0 = wb + 0;
  unsigned short* bc0 = wb + 32768;
  unsigned short* Wc1 = wb + 33024;
  unsigned short* bc1 = wb + 98560;
  unsigned short* We0 = wb + 98816;
  unsigned short* be0 = wb + 103936;
  unsigned short* We1 = wb + 103976;
  unsigned short* be1 = wb + 109096;
  unsigned short* We2 = wb + 109136;
  unsigned short* be2 = wb + 119376;
  unsigned short* We3 = wb + 119416;
  unsigned short* be3 = wb + 129656;
  unsigned short* WTc0  = wb + 131072;  // 256 x 128
  unsigned short* WTc1  = wb + 163840;  // 256 x 256
  unsigned short* WT40e0 = wb + 229376; // 48 x 128
  unsigned short* WT40e1 = wb + 235520; // 48 x 128
  unsigned short* WT40e2 = wb + 241664; // 48 x 256
  unsigned short* WT40e3 = wb + 253952; // 48 x 256

  dim3 B(256);
  k_probe<<<dim3(1), B, 0, stream>>>((const unsigned*)x_raw, ei, flags);
  k_zero<<<dim3(391), B, 0, stream>>>(cnt, NNODES);

  CvtParams p;
  const int srcIdx[13] = {0, 2, 3, 4, 5, 8, 9, 10, 11, 12, 13, 14, 15};
  unsigned short* dsts[13] = {xb, Wc0, bc0, Wc1, bc1, We0, be0, We1, be1, We2, be2, We3, be3};
  const int ns[13] = {NNODES * 128, 128 * 256, 256, 256 * 256, 256,
                      128 * 40, 40, 128 * 40, 40, 256 * 40, 40, 256 * 40, 40};
  for (int i = 0; i < 13; ++i) { p.src[i] = d_in[srcIdx[i]]; p.dst[i] = dsts[i]; p.n[i] = ns[i]; }
  k_cvt<<<dim3(1024, 13), B, 0, stream>>>(p, flags);
  k_transpose<<<dim3(128), B, 0, stream>>>(Wc0, WTc0, 128);
  k_transpose<<<dim3(256), B, 0, stream>>>(Wc1, WTc1, 256);
  k_transpose40<128><<<dim3(24), B, 0, stream>>>(We0, WT40e0);
  k_transpose40<128><<<dim3(24), B, 0, stream>>>(We1, WT40e1);
  k_transpose40<256><<<dim3(48), B, 0, stream>>>(We2, WT40e2);
  k_transpose40<256><<<dim3(48), B, 0, stream>>>(We3, WT40e3);

  k_count<<<dim3(6250), B, 0, stream>>>(ei, cnt, flags);
  k_dinv<<<dim3(391), B, 0, stream>>>(cnt, dinv);
  k_psum<<<dim3(391), B, 0, stream>>>(cnt, bsum);
  k_bscan<<<dim3(1), dim3(64), 0, stream>>>(bsum, bbase, offs);
  k_offs<<<dim3(391), B, 0, stream>>>(cnt, bbase, offs, cursor);
  k_fill<<<dim3(6250), B, 0, stream>>>(ei, cursor, csr_src, flags);

  // layer 0: on x
  k_exit_mfma<128, true><<<dim3(391), B, 0, stream>>>(xb, WT40e0, be0, out + 0 * 40, nullptr, dinv);
  // h1 = agg(x): gather dinv[src]
  k_agg<128, true><<<dim3(2048), B, 0, stream>>>(xb, hA, offs, csr_src, dinv);
  k_exit_mfma<128, true><<<dim3(391), B, 0, stream>>>(hA, WT40e1, be1, out + 1 * 40, nullptr, dinv);
  // hB = relu(h1 Wc0 + bc0) * dinv   (prescaled for next agg)
  k_mlp_mfma<128, true><<<dim3(782, 2), B, 0, stream>>>(hA, WTc0, bc0, hB, dinv);
  // h2 = agg(hB): prescaled input
  k_agg<256, false><<<dim3(2048), B, 0, stream>>>(hB, hA, offs, csr_src, dinv);
  k_exit_mfma<256, true><<<dim3(391), B, 0, stream>>>(hA, WT40e2, be2, out + 2 * 40, nullptr, dinv);
  k_mlp_mfma<256, false><<<dim3(782, 2), B, 0, stream>>>(hA, WTc1, bc1, hB, nullptr);
  // layer 3 push-through: P = (hc2 @ We3) * dinv
  k_exit_mfma<256, false><<<dim3(391), B, 0, stream>>>(hB, WT40e3, nullptr, nullptr, P, dinv);
  k_agg40<<<dim3(2048), B, 0, stream>>>(P, offs, csr_src, dinv, be3, out + 3 * 40);
}

// Round 3
// 770.315 us; speedup vs baseline: 1.7574x; 1.0562x over previous
//
#include <hip/hip_runtime.h>

#define NNODES 100000
#define NEDGES 1600000

typedef __attribute__((ext_vector_type(8))) short bf16x8;
typedef __attribute__((ext_vector_type(4))) float f32x4;

// ---------- bf16 helpers ----------
__device__ __forceinline__ float bf2f(unsigned v) {
  union { unsigned u; float f; } x; x.u = v << 16; return x.f;
}
__device__ __forceinline__ unsigned short f2bf(float f) {
  union { float f; unsigned u; } x; x.f = f;
  unsigned r = x.u + 0x7fffu + ((x.u >> 16) & 1u);
  return (unsigned short)(r >> 16);
}

// ---------- dtype probing ----------
__global__ void k_probe(const unsigned* __restrict__ xw, const int* __restrict__ ei,
                        int* __restrict__ flags) {
  __shared__ int cF, cI;
  if (threadIdx.x == 0) { cF = 0; cI = 0; }
  __syncthreads();
  int t = threadIdx.x;
  int hf = 0;
  for (int i = t; i < 2048; i += 256) {
    unsigned lo = xw[i] & 0xffffu;
    unsigned e = (lo >> 7) & 0xffu;
    if (e >= 0xC0u) hf++;
  }
  atomicAdd(&cF, hf);
  int hi = 0;
  if (ei[2 * t + 1] != 0) hi++;
  atomicAdd(&cI, hi);
  __syncthreads();
  if (threadIdx.x == 0) {
    flags[0] = (cF > 32) ? 1 : 0;
    flags[1] = (cI < 16) ? 1 : 0;
  }
}

__device__ __forceinline__ int edge_at(const int* __restrict__ ei, int j, int i64) {
  return i64 ? ei[2 * j] : ei[j];
}

// ---------- canonicalize float arrays to bf16 ----------
struct CvtParams {
  const void* src[13];
  unsigned short* dst[13];
  int n[13];
};

__global__ void k_cvt(CvtParams p, const int* __restrict__ flags) {
  int a = blockIdx.y;
  int n = p.n[a];
  int f32 = flags[0];
  const float* sf = (const float*)p.src[a];
  const unsigned short* sb = (const unsigned short*)p.src[a];
  unsigned short* d = p.dst[a];
  for (int i = blockIdx.x * blockDim.x + threadIdx.x; i < n; i += gridDim.x * blockDim.x) {
    d[i] = f32 ? f2bf(sf[i]) : sb[i];
  }
}

// transpose W[K,256] -> WT[256,K]
__global__ void k_transpose(const unsigned short* __restrict__ W,
                            unsigned short* __restrict__ WT, int K) {
  int idx = blockIdx.x * 256 + threadIdx.x;
  if (idx < K * 256) {
    int k = idx >> 8, c = idx & 255;
    WT[c * K + k] = W[idx];
  }
}

// transpose W[K,40] -> WT[48,K], rows 40..47 zero
template <int K>
__global__ void k_transpose40(const unsigned short* __restrict__ W,
                              unsigned short* __restrict__ WT) {
  int idx = blockIdx.x * 256 + threadIdx.x;
  if (idx < 48 * K) {
    int c = idx / K, k = idx % K;
    WT[idx] = (c < 40) ? W[k * 40 + c] : (unsigned short)0;
  }
}

__global__ void k_zero(int* __restrict__ p, int n) {
  int v = blockIdx.x * blockDim.x + threadIdx.x;
  if (v < n) p[v] = 0;
}

// ---------- graph preprocessing ----------
__global__ void k_count(const int* __restrict__ ei, int* __restrict__ cnt,
                        const int* __restrict__ flags) {
  int e = blockIdx.x * blockDim.x + threadIdx.x;
  if (e < NEDGES) {
    int i64 = flags[1];
    int d = edge_at(ei, NEDGES + e, i64);
    if ((unsigned)d < NNODES) atomicAdd(&cnt[d], 1);
  }
}

__global__ void k_dinv(const int* __restrict__ cnt, float* __restrict__ dinv) {
  int v = blockIdx.x * blockDim.x + threadIdx.x;
  if (v < NNODES) dinv[v] = rsqrtf((float)cnt[v] + 1.0f);
}

// ---------- parallel scan ----------
__global__ void k_psum(const int* __restrict__ cnt, int* __restrict__ bsum) {
  __shared__ int sw[4];
  int t = threadIdx.x;
  int i = blockIdx.x * 256 + t;
  int v = (i < NNODES) ? cnt[i] : 0;
  int x = v;
#pragma unroll
  for (int o = 1; o < 64; o <<= 1) {
    int y = __shfl_up(x, o, 64);
    if ((t & 63) >= o) x += y;
  }
  if ((t & 63) == 63) sw[t >> 6] = x;
  __syncthreads();
  if (t == 0) bsum[blockIdx.x] = sw[0] + sw[1] + sw[2] + sw[3];
}

__global__ void k_bscan(const int* __restrict__ bsum, int* __restrict__ bbase,
                        int* __restrict__ offs) {
  int l = threadIdx.x;
  int base = l * 7;
  int v[7];
  int s = 0;
#pragma unroll
  for (int k = 0; k < 7; ++k) {
    int j = base + k;
    v[k] = (j < 391) ? bsum[j] : 0;
    s += v[k];
  }
  int x = s;
#pragma unroll
  for (int o = 1; o < 64; o <<= 1) {
    int y = __shfl_up(x, o, 64);
    if (l >= o) x += y;
  }
  int excl = x - s;
#pragma unroll
  for (int k = 0; k < 7; ++k) {
    int j = base + k;
    if (j < 391) bbase[j] = excl;
    excl += v[k];
  }
  if (l == 63) offs[NNODES] = x;
}

__global__ void k_offs(const int* __restrict__ cnt, const int* __restrict__ bbase,
                       int* __restrict__ offs, int* __restrict__ cursor) {
  __shared__ int sw[4], swo[4];
  int t = threadIdx.x;
  int i = blockIdx.x * 256 + t;
  int v = (i < NNODES) ? cnt[i] : 0;
  int x = v;
#pragma unroll
  for (int o = 1; o < 64; o <<= 1) {
    int y = __shfl_up(x, o, 64);
    if ((t & 63) >= o) x += y;
  }
  if ((t & 63) == 63) sw[t >> 6] = x;
  __syncthreads();
  if (t == 0) {
    int a = 0;
#pragma unroll
    for (int w = 0; w < 4; ++w) { swo[w] = a; a += sw[w]; }
  }
  __syncthreads();
  if (i < NNODES) {
    int e = bbase[blockIdx.x] + swo[t >> 6] + x - v;
    offs[i] = e;
    cursor[i] = e;
  }
}

// fill CSR: src only (coefs come from dinv-prescaling)
__global__ void k_fill(const int* __restrict__ ei, int* __restrict__ cursor,
                       int* __restrict__ csr_src, const int* __restrict__ flags) {
  int e = blockIdx.x * blockDim.x + threadIdx.x;
  if (e < NEDGES) {
    int i64 = flags[1];
    int s = edge_at(ei, e, i64), d = edge_at(ei, NEDGES + e, i64);
    if ((unsigned)s < NNODES && (unsigned)d < NNODES) {
      int p = atomicAdd(&cursor[d], 1);
      if ((unsigned)p < NEDGES) csr_src[p] = s;
    }
  }
}

__device__ __forceinline__ void acc8(float (&acc)[8], uint4 u, float w) {
  acc[0] += w * bf2f(u.x & 0xffffu);
  acc[1] += w * bf2f(u.x >> 16);
  acc[2] += w * bf2f(u.y & 0xffffu);
  acc[3] += w * bf2f(u.y >> 16);
  acc[4] += w * bf2f(u.z & 0xffffu);
  acc[5] += w * bf2f(u.z >> 16);
  acc[6] += w * bf2f(u.w & 0xffffu);
  acc[7] += w * bf2f(u.w >> 16);
}

// ---------- aggregation: one wave per node, 16 B/lane multi-row gathers ----------
// D=128: 16 lanes/row, 4 rows/instr, 2 instrs/batch; D=256: 32 lanes/row,
// 2 rows/instr, 4 instrs/batch. 8 edges in flight per batch, clamped-index
// padding (weight 0) -> no tail loop. GDINV: gather dinv[src] (raw input);
// else input rows prescaled by dinv[src]. out[v] = dinv[v]*(edges + self).
template <int D, bool GDINV>
__global__ __launch_bounds__(256) void k_agg(
    const unsigned short* __restrict__ hin, unsigned short* __restrict__ hout,
    const int* __restrict__ offs, const int* __restrict__ csr_src,
    const float* __restrict__ dinv) {
  constexpr int LPR = D / 8;    // lanes per row (16 B each)
  constexpr int R = 64 / LPR;   // rows per gather instr
  constexpr int NB = 8 / R;     // gather instrs per 8-edge batch
  const int lane = threadIdx.x & 63;
  const int g = lane / LPR;     // row-group
  const int l = lane % LPR;     // lane within row
  const int v = (blockIdx.x * 256 + threadIdx.x) >> 6;
  if (v >= NNODES) return;

  float dv = dinv[v];
  const size_t vbase = (size_t)v * D + l * 8;
  uint4 su = *(const uint4*)(hin + vbase);
  float acc[8];
#pragma unroll
  for (int k = 0; k < 8; ++k) acc[k] = 0.f;
  acc8(acc, su, (g == 0) ? (GDINV ? dv : 1.f) : 0.f);

  int b0 = offs[v];
  int n = offs[v + 1] - b0;
  for (int i = 0; i < n; i += 8) {
    int s[NB];
    float wg[NB];
#pragma unroll
    for (int j = 0; j < NB; ++j) {
      int ei = i + j * R + g;
      int ec = (ei < n) ? ei : (n - 1);
      s[j] = csr_src[b0 + ec];
      wg[j] = (ei < n) ? (GDINV ? dinv[s[j]] : 1.f) : 0.f;
    }
    uint4 gu[NB];
#pragma unroll
    for (int j = 0; j < NB; ++j)
      gu[j] = *(const uint4*)(hin + (size_t)s[j] * D + l * 8);
#pragma unroll
    for (int j = 0; j < NB; ++j) acc8(acc, gu[j], wg[j]);
  }
#pragma unroll
  for (int k = 0; k < 8; ++k) {
#pragma unroll
    for (int o = LPR; o < 64; o <<= 1) acc[k] += __shfl_xor(acc[k], o, 64);
  }
  if (g == 0) {
    uint4 ov;
    ov.x = (unsigned)f2bf(dv * acc[0]) | ((unsigned)f2bf(dv * acc[1]) << 16);
    ov.y = (unsigned)f2bf(dv * acc[2]) | ((unsigned)f2bf(dv * acc[3]) << 16);
    ov.z = (unsigned)f2bf(dv * acc[4]) | ((unsigned)f2bf(dv * acc[5]) << 16);
    ov.w = (unsigned)f2bf(dv * acc[6]) | ((unsigned)f2bf(dv * acc[7]) << 16);
    *(uint4*)(hout + vbase) = ov;
  }
}

// ---------- width-40 aggregation + bias + log_softmax (layer 3) ----------
// P prescaled by dinv[row]. One wave per node; 2 row-groups of 32 lanes
// (lanes 0..19 active), 4 gather instrs x 2 rows = 8 edges per batch.
__global__ __launch_bounds__(256) void k_agg40(
    const unsigned short* __restrict__ P, const int* __restrict__ offs,
    const int* __restrict__ csr_src, const float* __restrict__ dinv,
    const unsigned short* __restrict__ bias, float* __restrict__ outp) {
  const int lane = threadIdx.x & 63;
  const int g = lane >> 5, l = lane & 31;
  const bool act = l < 20;
  const int v = (blockIdx.x * 256 + threadIdx.x) >> 6;
  if (v >= NNODES) return;

  float dv = dinv[v];
  float a0 = 0.f, a1 = 0.f;
  if (act && g == 0) {
    unsigned su = *(const unsigned*)(P + (size_t)v * 40 + l * 2);
    a0 = bf2f(su & 0xffffu);
    a1 = bf2f(su >> 16);
  }
  int b0 = offs[v];
  int n = offs[v + 1] - b0;
  for (int i = 0; i < n; i += 8) {
    int s[4];
    float wg[4];
#pragma unroll
    for (int j = 0; j < 4; ++j) {
      int ei = i + j * 2 + g;
      int ec = (ei < n) ? ei : (n - 1);
      s[j] = csr_src[b0 + ec];
      wg[j] = (ei < n) ? 1.f : 0.f;
    }
    unsigned gu[4];
#pragma unroll
    for (int j = 0; j < 4; ++j)
      gu[j] = act ? *(const unsigned*)(P + (size_t)s[j] * 40 + l * 2) : 0u;
#pragma unroll
    for (int j = 0; j < 4; ++j) {
      a0 += wg[j] * bf2f(gu[j] & 0xffffu);
      a1 += wg[j] * bf2f(gu[j] >> 16);
    }
  }
  // combine the two row-groups
  a0 += __shfl_xor(a0, 32, 64);
  a1 += __shfl_xor(a1, 32, 64);
  // bias + log_softmax over 40 cols (each 32-lane half has full sums)
  if (act) {
    a0 = dv * a0 + bf2f((unsigned)bias[l * 2]);
    a1 = dv * a1 + bf2f((unsigned)bias[l * 2 + 1]);
  }
  float m = act ? fmaxf(a0, a1) : -1e30f;
#pragma unroll
  for (int o = 16; o > 0; o >>= 1) m = fmaxf(m, __shfl_xor(m, o, 32));
  float ss = act ? (expf(a0 - m) + expf(a1 - m)) : 0.f;
#pragma unroll
  for (int o = 16; o > 0; o >>= 1) ss += __shfl_xor(ss, o, 32);
  float ls = logf(ss) + m;
  if (act && g == 0) {
    float2 o2;
    o2.x = a0 - ls;
    o2.y = a1 - ls;
    *(float2*)(outp + (size_t)v * 160 + l * 2) = o2;
  }
}

// ---------- MFMA continue GEMM: out = relu(A[N,K] @ W[K,256] + b) [* dinv] ----------
template <int K, bool SCALE>
__global__ __launch_bounds__(256) void k_mlp_mfma(
    const unsigned short* __restrict__ A, const unsigned short* __restrict__ WT,
    const unsigned short* __restrict__ bias, unsigned short* __restrict__ out,
    const float* __restrict__ dinv) {
  __shared__ short As[128 * 40];
  __shared__ short Bs[128 * 40];
  const int t = threadIdx.x;
  const int lane = t & 63, wv = t >> 6;
  const int m0 = blockIdx.x * 128;
  const int c0 = blockIdx.y * 128;
  const int mw = (wv >> 1) * 64, nw = (wv & 1) * 64;
  const int lr = lane & 15, lq = lane >> 4;

  f32x4 acc[4][4];
#pragma unroll
  for (int i = 0; i < 4; ++i)
#pragma unroll
    for (int j = 0; j < 4; ++j) acc[i][j] = (f32x4)0.f;

  for (int kc = 0; kc < K; kc += 32) {
    __syncthreads();
#pragma unroll
    for (int it = 0; it < 2; ++it) {
      int idx = t + it * 256;
      int row = idx >> 2, seg = idx & 3;
      uint4 u = make_uint4(0, 0, 0, 0);
      int gr = m0 + row;
      if (gr < NNODES) u = *(const uint4*)(A + (size_t)gr * K + kc + seg * 8);
      *(uint4*)&As[row * 40 + seg * 8] = u;
      uint4 v = *(const uint4*)(WT + (size_t)(c0 + row) * K + kc + seg * 8);
      *(uint4*)&Bs[row * 40 + seg * 8] = v;
    }
    __syncthreads();
    bf16x8 af[4], bfr[4];
#pragma unroll
    for (int i = 0; i < 4; ++i)
      af[i] = *(const bf16x8*)&As[(mw + 16 * i + lr) * 40 + lq * 8];
#pragma unroll
    for (int j = 0; j < 4; ++j)
      bfr[j] = *(const bf16x8*)&Bs[(nw + 16 * j + lr) * 40 + lq * 8];
#pragma unroll
    for (int i = 0; i < 4; ++i)
#pragma unroll
      for (int j = 0; j < 4; ++j)
        acc[i][j] = __builtin_amdgcn_mfma_f32_16x16x32_bf16(af[i], bfr[j], acc[i][j], 0, 0, 0);
  }

  float bv[4];
#pragma unroll
  for (int j = 0; j < 4; ++j) bv[j] = bf2f((unsigned)bias[c0 + nw + 16 * j + lr]);
#pragma unroll
  for (int i = 0; i < 4; ++i) {
    int rbase = m0 + mw + 16 * i + lq * 4;
#pragma unroll
    for (int r = 0; r < 4; ++r) {
      int row = rbase + r;
      if (row < NNODES) {
        float s = SCALE ? dinv[row] : 1.f;
#pragma unroll
        for (int j = 0; j < 4; ++j) {
          int col = c0 + nw + 16 * j + lr;
          float v = fmaxf(acc[i][j][r] + bv[j], 0.f) * s;
          out[(size_t)row * 256 + col] = f2bf(v);
        }
      }
    }
  }
}

// ---------- MFMA exit GEMM (+ optional fused log_softmax) ----------
// 128-row tiles (782 blocks), hoisted B-panel in LDS (padded stride K+8).
// !SOFTMAX: writes P = (A@We)*dinv[row], row-major [N][40] bf16.
template <int K, bool SOFTMAX>
__global__ __launch_bounds__(256) void k_exit_mfma(
    const unsigned short* __restrict__ A, const unsigned short* __restrict__ WT,
    const unsigned short* __restrict__ bias, float* __restrict__ outp,
    unsigned short* __restrict__ Pout, const float* __restrict__ dinv) {
  constexpr int KP = K + 8;
  __shared__ short As[128 * 40];
  __shared__ short Bs[48 * KP];
  const int t = threadIdx.x;
  const int lane = t & 63, wv = t >> 6;
  const int m0 = blockIdx.x * 128;
  const int mw = wv * 32;
  const int lr = lane & 15, lq = lane >> 4;

  // hoist B-panel once: 48 rows x K cols
  for (int idx = t; idx < 48 * (K / 8); idx += 256) {
    int row = idx / (K / 8), seg = idx % (K / 8);
    uint4 w = *(const uint4*)(WT + (size_t)row * K + seg * 8);
    *(uint4*)&Bs[row * KP + seg * 8] = w;
  }

  f32x4 acc[2][3];
#pragma unroll
  for (int i = 0; i < 2; ++i)
#pragma unroll
    for (int j = 0; j < 3; ++j) acc[i][j] = (f32x4)0.f;

  for (int kc = 0; kc < K; kc += 32) {
    __syncthreads();
#pragma unroll
    for (int it = 0; it < 2; ++it) {
      int idx = t + it * 256;
      int row = idx >> 2, seg = idx & 3;
      uint4 u = make_uint4(0, 0, 0, 0);
      int gr = m0 + row;
      if (gr < NNODES) u = *(const uint4*)(A + (size_t)gr * K + kc + seg * 8);
      *(uint4*)&As[row * 40 + seg * 8] = u;
    }
    __syncthreads();
    bf16x8 af[2], bfr[3];
#pragma unroll
    for (int i = 0; i < 2; ++i)
      af[i] = *(const bf16x8*)&As[(mw + 16 * i + lr) * 40 + lq * 8];
#pragma unroll
    for (int j = 0; j < 3; ++j)
      bfr[j] = *(const bf16x8*)&Bs[(16 * j + lr) * KP + kc + lq * 8];
#pragma unroll
    for (int i = 0; i < 2; ++i)
#pragma unroll
      for (int j = 0; j < 3; ++j)
        acc[i][j] = __builtin_amdgcn_mfma_f32_16x16x32_bf16(af[i], bfr[j], acc[i][j], 0, 0, 0);
  }

  if (SOFTMAX) {
    float bv0 = bf2f((unsigned)bias[lr]);
    float bv1 = bf2f((unsigned)bias[16 + lr]);
    float bv2 = (lr < 8) ? bf2f((unsigned)bias[32 + lr]) : 0.f;
#pragma unroll
    for (int i = 0; i < 2; ++i) {
#pragma unroll
      for (int r = 0; r < 4; ++r) {
        int row = m0 + mw + 16 * i + lq * 4 + r;
        float v0 = acc[i][0][r] + bv0;
        float v1 = acc[i][1][r] + bv1;
        float v2 = (lr < 8) ? (acc[i][2][r] + bv2) : -1e30f;
        float m = fmaxf(fmaxf(v0, v1), v2);
#pragma unroll
        for (int o = 8; o > 0; o >>= 1) m = fmaxf(m, __shfl_xor(m, o, 16));
        float ss = expf(v0 - m) + expf(v1 - m) + ((lr < 8) ? expf(v2 - m) : 0.f);
#pragma unroll
        for (int o = 8; o > 0; o >>= 1) ss += __shfl_xor(ss, o, 16);
        float ls = logf(ss) + m;
        if (row < NNODES) {
          outp[(size_t)row * 160 + lr] = v0 - ls;
          outp[(size_t)row * 160 + 16 + lr] = v1 - ls;
          if (lr < 8) outp[(size_t)row * 160 + 32 + lr] = v2 - ls;
        }
      }
    }
  } else {
#pragma unroll
    for (int i = 0; i < 2; ++i) {
#pragma unroll
      for (int r = 0; r < 4; ++r) {
        int row = m0 + mw + 16 * i + lq * 4 + r;
        if (row < NNODES) {
          float s = dinv[row];
          Pout[(size_t)row * 40 + lr] = f2bf(acc[i][0][r] * s);
          Pout[(size_t)row * 40 + 16 + lr] = f2bf(acc[i][1][r] * s);
          if (lr < 8) Pout[(size_t)row * 40 + 32 + lr] = f2bf(acc[i][2][r] * s);
        }
      }
    }
  }
}

// ---------- launch ----------
extern "C" void kernel_launch(void* const* d_in, const int* in_sizes, int n_in,
                              void* d_out, int out_size, void* d_ws, size_t ws_size,
                              hipStream_t stream) {
  const void* x_raw   = d_in[0];
  const int* ei       = (const int*)d_in[1];
  float* out          = (float*)d_out;

  char* ws = (char*)d_ws;
  int*   flags    = (int*)(ws + 0);
  int*   bsum     = (int*)(ws + 1024);
  int*   bbase    = (int*)(ws + 2816);
  int*   cnt      = (int*)(ws + 8192);
  int*   offs     = (int*)(ws + 524288);
  int*   cursor   = (int*)(ws + 1048576);
  float* dinv     = (float*)(ws + 1572864);
  int*   csr_src  = (int*)(ws + 2097152);                  // 6.4 MB src-only CSR
  unsigned short* xb = (unsigned short*)(ws + 16777216);   // N*128 bf16 (reused as P)
  unsigned short* wb = (unsigned short*)(ws + 45088768);   // weights
  unsigned short* hA = (unsigned short*)(ws + 48234496);   // N*256 bf16
  unsigned short* hB = (unsigned short*)(ws + 100663296);  // N*256 bf16
  unsigned short* P  = xb;

  unsigned short* Wc0 = wb + 0;
  unsigned short* bc0 = wb + 32768;
  unsigned short* Wc1 = wb + 33024;
  unsigned short* bc1 = wb + 98560;
  unsigned short* We0 = wb + 98816;
  unsigned short* be0 = wb + 103936;
  unsigned short* We1 = wb + 103976;
  unsigned short* be1 = wb + 109096;
  unsigned short* We2 = wb + 109136;
  unsigned short* be2 = wb + 119376;
  unsigned short* We3 = wb + 119416;
  unsigned short* be3 = wb + 129656;
  unsigned short* WTc0  = wb + 131072;  // 256 x 128
  unsigned short* WTc1  = wb + 163840;  // 256 x 256
  unsigned short* WT40e0 = wb + 229376; // 48 x 128
  unsigned short* WT40e1 = wb + 235520; // 48 x 128
  unsigned short* WT40e2 = wb + 241664; // 48 x 256
  unsigned short* WT40e3 = wb + 253952; // 48 x 256

  dim3 B(256);
  k_probe<<<dim3(1), B, 0, stream>>>((const unsigned*)x_raw, ei, flags);
  k_zero<<<dim3(391), B, 0, stream>>>(cnt, NNODES);

  CvtParams p;
  const int srcIdx[13] = {0, 2, 3, 4, 5, 8, 9, 10, 11, 12, 13, 14, 15};
  unsigned short* dsts[13] = {xb, Wc0, bc0, Wc1, bc1, We0, be0, We1, be1, We2, be2, We3, be3};
  const int ns[13] = {NNODES * 128, 128 * 256, 256, 256 * 256, 256,
                      128 * 40, 40, 128 * 40, 40, 256 * 40, 40, 256 * 40, 40};
  for (int i = 0; i < 13; ++i) { p.src[i] = d_in[srcIdx[i]]; p.dst[i] = dsts[i]; p.n[i] = ns[i]; }
  k_cvt<<<dim3(1024, 13), B, 0, stream>>>(p, flags);
  k_transpose<<<dim3(128), B, 0, stream>>>(Wc0, WTc0, 128);
  k_transpose<<<dim3(256), B, 0, stream>>>(Wc1, WTc1, 256);
  k_transpose40<128><<<dim3(24), B, 0, stream>>>(We0, WT40e0);
  k_transpose40<128><<<dim3(24), B, 0, stream>>>(We1, WT40e1);
  k_transpose40<256><<<dim3(48), B, 0, stream>>>(We2, WT40e2);
  k_transpose40<256><<<dim3(48), B, 0, stream>>>(We3, WT40e3);

  k_count<<<dim3(6250), B, 0, stream>>>(ei, cnt, flags);
  k_dinv<<<dim3(391), B, 0, stream>>>(cnt, dinv);
  k_psum<<<dim3(391), B, 0, stream>>>(cnt, bsum);
  k_bscan<<<dim3(1), dim3(64), 0, stream>>>(bsum, bbase, offs);
  k_offs<<<dim3(391), B, 0, stream>>>(cnt, bbase, offs, cursor);
  k_fill<<<dim3(6250), B, 0, stream>>>(ei, cursor, csr_src, flags);

  // layer 0: on x
  k_exit_mfma<128, true><<<dim3(782), B, 0, stream>>>(xb, WT40e0, be0, out + 0 * 40, nullptr, dinv);
  // h1 = agg(x): gather dinv[src]
  k_agg<128, true><<<dim3(25000), B, 0, stream>>>(xb, hA, offs, csr_src, dinv);
  k_exit_mfma<128, true><<<dim3(782), B, 0, stream>>>(hA, WT40e1, be1, out + 1 * 40, nullptr, dinv);
  // hB = relu(h1 Wc0 + bc0) * dinv   (prescaled for next agg)
  k_mlp_mfma<128, true><<<dim3(782, 2), B, 0, stream>>>(hA, WTc0, bc0, hB, dinv);
  // h2 = agg(hB): prescaled input
  k_agg<256, false><<<dim3(25000), B, 0, stream>>>(hB, hA, offs, csr_src, dinv);
  k_exit_mfma<256, true><<<dim3(782), B, 0, stream>>>(hA, WT40e2, be2, out + 2 * 40, nullptr, dinv);
  k_mlp_mfma<256, false><<<dim3(782, 2), B, 0, stream>>>(hA, WTc1, bc1, hB, nullptr);
  // layer 3 push-through: P = (hc2 @ We3) * dinv
  k_exit_mfma<256, false><<<dim3(782), B, 0, stream>>>(hB, WT40e3, nullptr, nullptr, P, dinv);
  k_agg40<<<dim3(25000), B, 0, stream>>>(P, offs, csr_src, dinv, be3, out + 3 * 40);
}

// Round 4
// 630.399 us; speedup vs baseline: 2.1474x; 1.2219x over previous
//
#include <hip/hip_runtime.h>

#define NNODES 100000
#define NEDGES 1600000
#define NBKT 782          // buckets of 128 nodes: 782*128 = 100096 >= NNODES

typedef __attribute__((ext_vector_type(8))) short bf16x8;
typedef __attribute__((ext_vector_type(4))) float f32x4;

// ---------- bf16 helpers ----------
__device__ __forceinline__ float bf2f(unsigned v) {
  union { unsigned u; float f; } x; x.u = v << 16; return x.f;
}
__device__ __forceinline__ unsigned short f2bf(float f) {
  union { float f; unsigned u; } x; x.f = f;
  unsigned r = x.u + 0x7fffu + ((x.u >> 16) & 1u);
  return (unsigned short)(r >> 16);
}

// ---------- dtype probing ----------
__global__ void k_probe(const unsigned* __restrict__ xw, const int* __restrict__ ei,
                        int* __restrict__ flags) {
  __shared__ int cF, cI;
  if (threadIdx.x == 0) { cF = 0; cI = 0; }
  __syncthreads();
  int t = threadIdx.x;
  int hf = 0;
  for (int i = t; i < 2048; i += 256) {
    unsigned lo = xw[i] & 0xffffu;
    unsigned e = (lo >> 7) & 0xffu;
    if (e >= 0xC0u) hf++;
  }
  atomicAdd(&cF, hf);
  int hi = 0;
  if (ei[2 * t + 1] != 0) hi++;
  atomicAdd(&cI, hi);
  __syncthreads();
  if (threadIdx.x == 0) {
    flags[0] = (cF > 32) ? 1 : 0;
    flags[1] = (cI < 16) ? 1 : 0;
  }
}

__device__ __forceinline__ int edge_at(const int* __restrict__ ei, int j, int i64) {
  return i64 ? ei[2 * j] : ei[j];
}

// ---------- canonicalize float arrays to bf16 ----------
struct CvtParams {
  const void* src[13];
  unsigned short* dst[13];
  int n[13];
};

__global__ void k_cvt(CvtParams p, const int* __restrict__ flags) {
  int a = blockIdx.y;
  int n = p.n[a];
  int f32 = flags[0];
  const float* sf = (const float*)p.src[a];
  const unsigned short* sb = (const unsigned short*)p.src[a];
  unsigned short* d = p.dst[a];
  for (int i = blockIdx.x * blockDim.x + threadIdx.x; i < n; i += gridDim.x * blockDim.x) {
    d[i] = f32 ? f2bf(sf[i]) : sb[i];
  }
}

// transpose W[K,256] -> WT[256,K]
__global__ void k_transpose(const unsigned short* __restrict__ W,
                            unsigned short* __restrict__ WT, int K) {
  int idx = blockIdx.x * 256 + threadIdx.x;
  if (idx < K * 256) {
    int k = idx >> 8, c = idx & 255;
    WT[c * K + k] = W[idx];
  }
}

// transpose W[K,40] -> WT[48,K], rows 40..47 zero
template <int K>
__global__ void k_transpose40(const unsigned short* __restrict__ W,
                              unsigned short* __restrict__ WT) {
  int idx = blockIdx.x * 256 + threadIdx.x;
  if (idx < 48 * K) {
    int c = idx / K, k = idx % K;
    WT[idx] = (c < 40) ? W[k * 40 + c] : (unsigned short)0;
  }
}

__global__ void k_zero(int* __restrict__ p, int n) {
  int v = blockIdx.x * blockDim.x + threadIdx.x;
  if (v < n) p[v] = 0;
}

// ---------- bucketed CSR build (no global per-edge atomics) ----------
// Bucket b = dst >> 7 covers nodes [128b, 128b+128). Record: (dstloc<<17)|src.

// pass 1: per-block LDS histogram over buckets -> aggregated global adds
__global__ __launch_bounds__(256) void k_bcnt(const int* __restrict__ ei,
                                              int* __restrict__ bcnt,
                                              const int* __restrict__ flags) {
  __shared__ int h[NBKT];
  int t = threadIdx.x;
  for (int i = t; i < NBKT; i += 256) h[i] = 0;
  __syncthreads();
  int i64 = flags[1];
  int e0 = blockIdx.x * 4096;
#pragma unroll
  for (int k = 0; k < 16; ++k) {
    int e = e0 + t + k * 256;
    if (e < NEDGES) {
      int d = edge_at(ei, NEDGES + e, i64);
      if ((unsigned)d < NNODES) atomicAdd(&h[d >> 7], 1);
    }
  }
  __syncthreads();
  for (int i = t; i < NBKT; i += 256)
    if (h[i]) atomicAdd(&bcnt[i], h[i]);
}

// scan 782 bucket counts -> bbase[0..782], init gcur
__global__ void k_bscan2(const int* __restrict__ bcnt, int* __restrict__ bbase,
                         int* __restrict__ gcur) {
  int l = threadIdx.x;  // 64 lanes
  int v[13];
  int s = 0;
#pragma unroll
  for (int k = 0; k < 13; ++k) {
    int j = l * 13 + k;
    v[k] = (j < NBKT) ? bcnt[j] : 0;
    s += v[k];
  }
  int x = s;
#pragma unroll
  for (int o = 1; o < 64; o <<= 1) {
    int y = __shfl_up(x, o, 64);
    if (l >= o) x += y;
  }
  int excl = x - s;
#pragma unroll
  for (int k = 0; k < 13; ++k) {
    int j = l * 13 + k;
    if (j < NBKT) { bbase[j] = excl; gcur[j] = excl; }
    excl += v[k];
  }
  if (l == 63) bbase[NBKT] = x;
}

// pass 2: stage records bucket-contiguously (block-aggregated reservations)
__global__ __launch_bounds__(256) void k_bstage(const int* __restrict__ ei,
                                                int* __restrict__ gcur,
                                                int* __restrict__ stage,
                                                const int* __restrict__ flags) {
  __shared__ int h[NBKT];
  __shared__ int base[NBKT];
  int t = threadIdx.x;
  for (int i = t; i < NBKT; i += 256) h[i] = 0;
  __syncthreads();
  int i64 = flags[1];
  int e0 = blockIdx.x * 4096;
  int bkt[16], lp[16], rec[16];
#pragma unroll
  for (int k = 0; k < 16; ++k) {
    bkt[k] = -1;
    int e = e0 + t + k * 256;
    if (e < NEDGES) {
      int d = edge_at(ei, NEDGES + e, i64);
      if ((unsigned)d < NNODES) {
        int s = edge_at(ei, e, i64);
        if ((unsigned)s >= NNODES) s = NNODES - 1;
        bkt[k] = d >> 7;
        rec[k] = ((d & 127) << 17) | s;
        lp[k] = atomicAdd(&h[bkt[k]], 1);
      }
    }
  }
  __syncthreads();
  for (int i = t; i < NBKT; i += 256)
    base[i] = h[i] ? atomicAdd(&gcur[i], h[i]) : 0;
  __syncthreads();
#pragma unroll
  for (int k = 0; k < 16; ++k)
    if (bkt[k] >= 0) stage[base[bkt[k]] + lp[k]] = rec[k];
}

// pass 3: one block per bucket -> offs, dinv, csr_src (LDS atomics only)
__global__ __launch_bounds__(256) void k_bplace(const int* __restrict__ stage,
                                                const int* __restrict__ bbase,
                                                int* __restrict__ offs,
                                                float* __restrict__ dinv,
                                                int* __restrict__ csr_src) {
  __shared__ int h[128];
  __shared__ int cur[128];
  int b = blockIdx.x;
  int t = threadIdx.x;
  int n0 = b * 128;
  int NN = NNODES - n0; if (NN > 128) NN = 128;
  int s0 = bbase[b], s1 = bbase[b + 1];
  int cnt = s1 - s0;
  if (t < 128) h[t] = 0;
  __syncthreads();
  for (int i = t; i < cnt; i += 256) {
    int rec = stage[s0 + i];
    atomicAdd(&h[rec >> 17], 1);
  }
  __syncthreads();
  if (t < 64) {
    int a = h[2 * t], c = h[2 * t + 1];
    int s = a + c;
    int x = s;
#pragma unroll
    for (int o = 1; o < 64; o <<= 1) {
      int y = __shfl_up(x, o, 64);
      if (t >= o) x += y;
    }
    int excl = s0 + x - s;
    cur[2 * t] = excl;
    cur[2 * t + 1] = excl + a;
    if (2 * t < NN) {
      offs[n0 + 2 * t] = excl;
      dinv[n0 + 2 * t] = rsqrtf((float)a + 1.0f);
    }
    if (2 * t + 1 < NN) {
      offs[n0 + 2 * t + 1] = excl + a;
      dinv[n0 + 2 * t + 1] = rsqrtf((float)c + 1.0f);
    }
  }
  if (b == NBKT - 1 && t == 0) offs[NNODES] = s1;
  __syncthreads();
  for (int i = t; i < cnt; i += 256) {
    int rec = stage[s0 + i];
    int pos = atomicAdd(&cur[rec >> 17], 1);
    csr_src[pos] = rec & 0x1FFFF;
  }
}

__device__ __forceinline__ void acc8(float (&acc)[8], uint4 u, float w) {
  acc[0] += w * bf2f(u.x & 0xffffu);
  acc[1] += w * bf2f(u.x >> 16);
  acc[2] += w * bf2f(u.y & 0xffffu);
  acc[3] += w * bf2f(u.y >> 16);
  acc[4] += w * bf2f(u.z & 0xffffu);
  acc[5] += w * bf2f(u.z >> 16);
  acc[6] += w * bf2f(u.w & 0xffffu);
  acc[7] += w * bf2f(u.w >> 16);
}

// ---------- aggregation: one wave per node, 16 B/lane multi-row gathers ----------
template <int D, bool GDINV>
__global__ __launch_bounds__(256) void k_agg(
    const unsigned short* __restrict__ hin, unsigned short* __restrict__ hout,
    const int* __restrict__ offs, const int* __restrict__ csr_src,
    const float* __restrict__ dinv) {
  constexpr int LPR = D / 8;    // lanes per row (16 B each)
  constexpr int R = 64 / LPR;   // rows per gather instr
  constexpr int NB = 8 / R;     // gather instrs per 8-edge batch
  const int lane = threadIdx.x & 63;
  const int g = lane / LPR;     // row-group
  const int l = lane % LPR;     // lane within row
  const int v = (blockIdx.x * 256 + threadIdx.x) >> 6;
  if (v >= NNODES) return;

  float dv = dinv[v];
  const size_t vbase = (size_t)v * D + l * 8;
  uint4 su = *(const uint4*)(hin + vbase);
  float acc[8];
#pragma unroll
  for (int k = 0; k < 8; ++k) acc[k] = 0.f;
  acc8(acc, su, (g == 0) ? (GDINV ? dv : 1.f) : 0.f);

  int b0 = offs[v];
  int n = offs[v + 1] - b0;
  for (int i = 0; i < n; i += 8) {
    int s[NB];
    float wg[NB];
#pragma unroll
    for (int j = 0; j < NB; ++j) {
      int ei = i + j * R + g;
      int ec = (ei < n) ? ei : (n - 1);
      s[j] = csr_src[b0 + ec];
      wg[j] = (ei < n) ? (GDINV ? dinv[s[j]] : 1.f) : 0.f;
    }
    uint4 gu[NB];
#pragma unroll
    for (int j = 0; j < NB; ++j)
      gu[j] = *(const uint4*)(hin + (size_t)s[j] * D + l * 8);
#pragma unroll
    for (int j = 0; j < NB; ++j) acc8(acc, gu[j], wg[j]);
  }
#pragma unroll
  for (int k = 0; k < 8; ++k) {
#pragma unroll
    for (int o = LPR; o < 64; o <<= 1) acc[k] += __shfl_xor(acc[k], o, 64);
  }
  if (g == 0) {
    uint4 ov;
    ov.x = (unsigned)f2bf(dv * acc[0]) | ((unsigned)f2bf(dv * acc[1]) << 16);
    ov.y = (unsigned)f2bf(dv * acc[2]) | ((unsigned)f2bf(dv * acc[3]) << 16);
    ov.z = (unsigned)f2bf(dv * acc[4]) | ((unsigned)f2bf(dv * acc[5]) << 16);
    ov.w = (unsigned)f2bf(dv * acc[6]) | ((unsigned)f2bf(dv * acc[7]) << 16);
    *(uint4*)(hout + vbase) = ov;
  }
}

// ---------- width-40 aggregation + bias + log_softmax (layer 3) ----------
__global__ __launch_bounds__(256) void k_agg40(
    const unsigned short* __restrict__ P, const int* __restrict__ offs,
    const int* __restrict__ csr_src, const float* __restrict__ dinv,
    const unsigned short* __restrict__ bias, float* __restrict__ outp) {
  const int lane = threadIdx.x & 63;
  const int g = lane >> 5, l = lane & 31;
  const bool act = l < 20;
  const int v = (blockIdx.x * 256 + threadIdx.x) >> 6;
  if (v >= NNODES) return;

  float dv = dinv[v];
  float a0 = 0.f, a1 = 0.f;
  if (act && g == 0) {
    unsigned su = *(const unsigned*)(P + (size_t)v * 40 + l * 2);
    a0 = bf2f(su & 0xffffu);
    a1 = bf2f(su >> 16);
  }
  int b0 = offs[v];
  int n = offs[v + 1] - b0;
  for (int i = 0; i < n; i += 8) {
    int s[4];
    float wg[4];
#pragma unroll
    for (int j = 0; j < 4; ++j) {
      int ei = i + j * 2 + g;
      int ec = (ei < n) ? ei : (n - 1);
      s[j] = csr_src[b0 + ec];
      wg[j] = (ei < n) ? 1.f : 0.f;
    }
    unsigned gu[4];
#pragma unroll
    for (int j = 0; j < 4; ++j)
      gu[j] = act ? *(const unsigned*)(P + (size_t)s[j] * 40 + l * 2) : 0u;
#pragma unroll
    for (int j = 0; j < 4; ++j) {
      a0 += wg[j] * bf2f(gu[j] & 0xffffu);
      a1 += wg[j] * bf2f(gu[j] >> 16);
    }
  }
  a0 += __shfl_xor(a0, 32, 64);
  a1 += __shfl_xor(a1, 32, 64);
  if (act) {
    a0 = dv * a0 + bf2f((unsigned)bias[l * 2]);
    a1 = dv * a1 + bf2f((unsigned)bias[l * 2 + 1]);
  }
  float m = act ? fmaxf(a0, a1) : -1e30f;
#pragma unroll
  for (int o = 16; o > 0; o >>= 1) m = fmaxf(m, __shfl_xor(m, o, 32));
  float ss = act ? (expf(a0 - m) + expf(a1 - m)) : 0.f;
#pragma unroll
  for (int o = 16; o > 0; o >>= 1) ss += __shfl_xor(ss, o, 32);
  float ls = logf(ss) + m;
  if (act && g == 0) {
    float2 o2;
    o2.x = a0 - ls;
    o2.y = a1 - ls;
    *(float2*)(outp + (size_t)v * 160 + l * 2) = o2;
  }
}

// ---------- MFMA continue GEMM: out = relu(A[N,K] @ W[K,256] + b) [* dinv] ----------
template <int K, bool SCALE>
__global__ __launch_bounds__(256) void k_mlp_mfma(
    const unsigned short* __restrict__ A, const unsigned short* __restrict__ WT,
    const unsigned short* __restrict__ bias, unsigned short* __restrict__ out,
    const float* __restrict__ dinv) {
  __shared__ short As[128 * 40];
  __shared__ short Bs[128 * 40];
  const int t = threadIdx.x;
  const int lane = t & 63, wv = t >> 6;
  const int m0 = blockIdx.x * 128;
  const int c0 = blockIdx.y * 128;
  const int mw = (wv >> 1) * 64, nw = (wv & 1) * 64;
  const int lr = lane & 15, lq = lane >> 4;

  f32x4 acc[4][4];
#pragma unroll
  for (int i = 0; i < 4; ++i)
#pragma unroll
    for (int j = 0; j < 4; ++j) acc[i][j] = (f32x4)0.f;

  for (int kc = 0; kc < K; kc += 32) {
    __syncthreads();
#pragma unroll
    for (int it = 0; it < 2; ++it) {
      int idx = t + it * 256;
      int row = idx >> 2, seg = idx & 3;
      uint4 u = make_uint4(0, 0, 0, 0);
      int gr = m0 + row;
      if (gr < NNODES) u = *(const uint4*)(A + (size_t)gr * K + kc + seg * 8);
      *(uint4*)&As[row * 40 + seg * 8] = u;
      uint4 v = *(const uint4*)(WT + (size_t)(c0 + row) * K + kc + seg * 8);
      *(uint4*)&Bs[row * 40 + seg * 8] = v;
    }
    __syncthreads();
    bf16x8 af[4], bfr[4];
#pragma unroll
    for (int i = 0; i < 4; ++i)
      af[i] = *(const bf16x8*)&As[(mw + 16 * i + lr) * 40 + lq * 8];
#pragma unroll
    for (int j = 0; j < 4; ++j)
      bfr[j] = *(const bf16x8*)&Bs[(nw + 16 * j + lr) * 40 + lq * 8];
#pragma unroll
    for (int i = 0; i < 4; ++i)
#pragma unroll
      for (int j = 0; j < 4; ++j)
        acc[i][j] = __builtin_amdgcn_mfma_f32_16x16x32_bf16(af[i], bfr[j], acc[i][j], 0, 0, 0);
  }

  float bv[4];
#pragma unroll
  for (int j = 0; j < 4; ++j) bv[j] = bf2f((unsigned)bias[c0 + nw + 16 * j + lr]);
#pragma unroll
  for (int i = 0; i < 4; ++i) {
    int rbase = m0 + mw + 16 * i + lq * 4;
#pragma unroll
    for (int r = 0; r < 4; ++r) {
      int row = rbase + r;
      if (row < NNODES) {
        float s = SCALE ? dinv[row] : 1.f;
#pragma unroll
        for (int j = 0; j < 4; ++j) {
          int col = c0 + nw + 16 * j + lr;
          float v = fmaxf(acc[i][j][r] + bv[j], 0.f) * s;
          out[(size_t)row * 256 + col] = f2bf(v);
        }
      }
    }
  }
}

// ---------- MFMA exit GEMM (+ optional fused log_softmax) ----------
// 128-row tiles, hoisted B-panel in LDS (padded stride K+8).
template <int K, bool SOFTMAX>
__global__ __launch_bounds__(256) void k_exit_mfma(
    const unsigned short* __restrict__ A, const unsigned short* __restrict__ WT,
    const unsigned short* __restrict__ bias, float* __restrict__ outp,
    unsigned short* __restrict__ Pout, const float* __restrict__ dinv) {
  constexpr int KP = K + 8;
  __shared__ short As[128 * 40];
  __shared__ short Bs[48 * KP];
  const int t = threadIdx.x;
  const int lane = t & 63, wv = t >> 6;
  const int m0 = blockIdx.x * 128;
  const int mw = wv * 32;
  const int lr = lane & 15, lq = lane >> 4;

  for (int idx = t; idx < 48 * (K / 8); idx += 256) {
    int row = idx / (K / 8), seg = idx % (K / 8);
    uint4 w = *(const uint4*)(WT + (size_t)row * K + seg * 8);
    *(uint4*)&Bs[row * KP + seg * 8] = w;
  }

  f32x4 acc[2][3];
#pragma unroll
  for (int i = 0; i < 2; ++i)
#pragma unroll
    for (int j = 0; j < 3; ++j) acc[i][j] = (f32x4)0.f;

  for (int kc = 0; kc < K; kc += 32) {
    __syncthreads();
#pragma unroll
    for (int it = 0; it < 2; ++it) {
      int idx = t + it * 256;
      int row = idx >> 2, seg = idx & 3;
      uint4 u = make_uint4(0, 0, 0, 0);
      int gr = m0 + row;
      if (gr < NNODES) u = *(const uint4*)(A + (size_t)gr * K + kc + seg * 8);
      *(uint4*)&As[row * 40 + seg * 8] = u;
    }
    __syncthreads();
    bf16x8 af[2], bfr[3];
#pragma unroll
    for (int i = 0; i < 2; ++i)
      af[i] = *(const bf16x8*)&As[(mw + 16 * i + lr) * 40 + lq * 8];
#pragma unroll
    for (int j = 0; j < 3; ++j)
      bfr[j] = *(const bf16x8*)&Bs[(16 * j + lr) * KP + kc + lq * 8];
#pragma unroll
    for (int i = 0; i < 2; ++i)
#pragma unroll
      for (int j = 0; j < 3; ++j)
        acc[i][j] = __builtin_amdgcn_mfma_f32_16x16x32_bf16(af[i], bfr[j], acc[i][j], 0, 0, 0);
  }

  if (SOFTMAX) {
    float bv0 = bf2f((unsigned)bias[lr]);
    float bv1 = bf2f((unsigned)bias[16 + lr]);
    float bv2 = (lr < 8) ? bf2f((unsigned)bias[32 + lr]) : 0.f;
#pragma unroll
    for (int i = 0; i < 2; ++i) {
#pragma unroll
      for (int r = 0; r < 4; ++r) {
        int row = m0 + mw + 16 * i + lq * 4 + r;
        float v0 = acc[i][0][r] + bv0;
        float v1 = acc[i][1][r] + bv1;
        float v2 = (lr < 8) ? (acc[i][2][r] + bv2) : -1e30f;
        float m = fmaxf(fmaxf(v0, v1), v2);
#pragma unroll
        for (int o = 8; o > 0; o >>= 1) m = fmaxf(m, __shfl_xor(m, o, 16));
        float ss = expf(v0 - m) + expf(v1 - m) + ((lr < 8) ? expf(v2 - m) : 0.f);
#pragma unroll
        for (int o = 8; o > 0; o >>= 1) ss += __shfl_xor(ss, o, 16);
        float ls = logf(ss) + m;
        if (row < NNODES) {
          outp[(size_t)row * 160 + lr] = v0 - ls;
          outp[(size_t)row * 160 + 16 + lr] = v1 - ls;
          if (lr < 8) outp[(size_t)row * 160 + 32 + lr] = v2 - ls;
        }
      }
    }
  } else {
#pragma unroll
    for (int i = 0; i < 2; ++i) {
#pragma unroll
      for (int r = 0; r < 4; ++r) {
        int row = m0 + mw + 16 * i + lq * 4 + r;
        if (row < NNODES) {
          float s = dinv[row];
          Pout[(size_t)row * 40 + lr] = f2bf(acc[i][0][r] * s);
          Pout[(size_t)row * 40 + 16 + lr] = f2bf(acc[i][1][r] * s);
          if (lr < 8) Pout[(size_t)row * 40 + 32 + lr] = f2bf(acc[i][2][r] * s);
        }
      }
    }
  }
}

// ---------- launch ----------
extern "C" void kernel_launch(void* const* d_in, const int* in_sizes, int n_in,
                              void* d_out, int out_size, void* d_ws, size_t ws_size,
                              hipStream_t stream) {
  const void* x_raw   = d_in[0];
  const int* ei       = (const int*)d_in[1];
  float* out          = (float*)d_out;

  char* ws = (char*)d_ws;
  int*   flags    = (int*)(ws + 0);
  int*   bcnt     = (int*)(ws + 4096);      // 782 ints
  int*   gcur     = (int*)(ws + 8192);      // 782 ints
  int*   bbase    = (int*)(ws + 12288);     // 783 ints
  float* dinv     = (float*)(ws + 524288);  // 400 KB
  int*   offs     = (int*)(ws + 1048576);   // 400 KB + 4
  int*   csr_src  = (int*)(ws + 2097152);   // 6.4 MB
  int*   stage    = (int*)(ws + 8650752);   // 6.4 MB staged recs
  unsigned short* xb = (unsigned short*)(ws + 16777216);   // N*128 bf16 (reused as P)
  unsigned short* wb = (unsigned short*)(ws + 45088768);   // weights
  unsigned short* hA = (unsigned short*)(ws + 48234496);   // N*256 bf16
  unsigned short* hB = (unsigned short*)(ws + 100663296);  // N*256 bf16
  unsigned short* P  = xb;

  unsigned short* Wc0 = wb + 0;
  unsigned short* bc0 = wb + 32768;
  unsigned short* Wc1 = wb + 33024;
  unsigned short* bc1 = wb + 98560;
  unsigned short* We0 = wb + 98816;
  unsigned short* be0 = wb + 103936;
  unsigned short* We1 = wb + 103976;
  unsigned short* be1 = wb + 109096;
  unsigned short* We2 = wb + 109136;
  unsigned short* be2 = wb + 119376;
  unsigned short* We3 = wb + 119416;
  unsigned short* be3 = wb + 129656;
  unsigned short* WTc0  = wb + 131072;  // 256 x 128
  unsigned short* WTc1  = wb + 163840;  // 256 x 256
  unsigned short* WT40e0 = wb + 229376; // 48 x 128
  unsigned short* WT40e1 = wb + 235520; // 48 x 128
  unsigned short* WT40e2 = wb + 241664; // 48 x 256
  unsigned short* WT40e3 = wb + 253952; // 48 x 256

  dim3 B(256);
  k_probe<<<dim3(1), B, 0, stream>>>((const unsigned*)x_raw, ei, flags);
  k_zero<<<dim3(4), B, 0, stream>>>(bcnt, NBKT);

  CvtParams p;
  const int srcIdx[13] = {0, 2, 3, 4, 5, 8, 9, 10, 11, 12, 13, 14, 15};
  unsigned short* dsts[13] = {xb, Wc0, bc0, Wc1, bc1, We0, be0, We1, be1, We2, be2, We3, be3};
  const int ns[13] = {NNODES * 128, 128 * 256, 256, 256 * 256, 256,
                      128 * 40, 40, 128 * 40, 40, 256 * 40, 40, 256 * 40, 40};
  for (int i = 0; i < 13; ++i) { p.src[i] = d_in[srcIdx[i]]; p.dst[i] = dsts[i]; p.n[i] = ns[i]; }
  k_cvt<<<dim3(1024, 13), B, 0, stream>>>(p, flags);
  k_transpose<<<dim3(128), B, 0, stream>>>(Wc0, WTc0, 128);
  k_transpose<<<dim3(256), B, 0, stream>>>(Wc1, WTc1, 256);
  k_transpose40<128><<<dim3(24), B, 0, stream>>>(We0, WT40e0);
  k_transpose40<128><<<dim3(24), B, 0, stream>>>(We1, WT40e1);
  k_transpose40<256><<<dim3(48), B, 0, stream>>>(We2, WT40e2);
  k_transpose40<256><<<dim3(48), B, 0, stream>>>(We3, WT40e3);

  // bucketed CSR build: count -> scan -> stage -> place
  k_bcnt<<<dim3(391), B, 0, stream>>>(ei, bcnt, flags);
  k_bscan2<<<dim3(1), dim3(64), 0, stream>>>(bcnt, bbase, gcur);
  k_bstage<<<dim3(391), B, 0, stream>>>(ei, gcur, stage, flags);
  k_bplace<<<dim3(NBKT), B, 0, stream>>>(stage, bbase, offs, dinv, csr_src);

  // layer 0: on x
  k_exit_mfma<128, true><<<dim3(782), B, 0, stream>>>(xb, WT40e0, be0, out + 0 * 40, nullptr, dinv);
  // h1 = agg(x): gather dinv[src]
  k_agg<128, true><<<dim3(25000), B, 0, stream>>>(xb, hA, offs, csr_src, dinv);
  k_exit_mfma<128, true><<<dim3(782), B, 0, stream>>>(hA, WT40e1, be1, out + 1 * 40, nullptr, dinv);
  // hB = relu(h1 Wc0 + bc0) * dinv   (prescaled for next agg)
  k_mlp_mfma<128, true><<<dim3(782, 2), B, 0, stream>>>(hA, WTc0, bc0, hB, dinv);
  // h2 = agg(hB): prescaled input
  k_agg<256, false><<<dim3(25000), B, 0, stream>>>(hB, hA, offs, csr_src, dinv);
  k_exit_mfma<256, true><<<dim3(782), B, 0, stream>>>(hA, WT40e2, be2, out + 2 * 40, nullptr, dinv);
  k_mlp_mfma<256, false><<<dim3(782, 2), B, 0, stream>>>(hA, WTc1, bc1, hB, nullptr);
  // layer 3 push-through: P = (hc2 @ We3) * dinv
  k_exit_mfma<256, false><<<dim3(782), B, 0, stream>>>(hB, WT40e3, nullptr, nullptr, P, dinv);
  k_agg40<<<dim3(25000), B, 0, stream>>>(P, offs, csr_src, dinv, be3, out + 3 * 40);
}